// Round 5
// baseline (1023.235 us; speedup 1.0000x reference)
//
#include <hip/hip_runtime.h>

#define DEVI static __device__ __forceinline__

typedef __attribute__((ext_vector_type(4))) float f32x4;
typedef __attribute__((ext_vector_type(8))) short short8;
typedef __attribute__((ext_vector_type(4))) short short4v;
typedef __attribute__((ext_vector_type(8))) __bf16 bf16x8;

#define N_    4096
#define KNN_  20
#define NPTS  32768

DEVI unsigned short f2bf(float f){
  unsigned u = __float_as_uint(f);
  u += 0x7FFFu + ((u >> 16) & 1u);
  return (unsigned short)(u >> 16);
}
DEVI float bf2f(unsigned short s){ return __uint_as_float(((unsigned)s) << 16); }
DEVI float bf2fs(short s){ return __uint_as_float(((unsigned)(unsigned short)s) << 16); }
DEVI unsigned umin32(unsigned a, unsigned b){ return a < b ? a : b; }
DEVI unsigned umax32(unsigned a, unsigned b){ return a > b ? a : b; }

DEVI f32x4 mfma16(short8 a, short8 b, f32x4 c){
  return __builtin_amdgcn_mfma_f32_16x16x32_bf16(
      __builtin_bit_cast(bf16x8, a), __builtin_bit_cast(bf16x8, b), c, 0, 0, 0);
}

// LDS row-major bf16 tiles, XOR swizzle on 16B granules
DEVI short8 lds_frag(const unsigned short* buf, int row, int k0, int strideS, int swzMask){
  return *(const short8*)(buf + row*strideS + (k0 ^ ((row & swzMask) << 3)));
}
DEVI void lds_put8(unsigned short* buf, int row, int k0, int strideS, int swzMask, short8 v){
  *(short8*)(buf + row*strideS + (k0 ^ ((row & swzMask) << 3))) = v;
}
DEVI void lds_put4(unsigned short* buf, int row, int col, int strideS, int swzMask, short4v v){
  *(short4v*)(buf + row*strideS + (col ^ ((row & swzMask) << 3))) = v;
}

// blind sorted-insert into ascending top-20 (min/max identity, no-op if K>=a[19])
DEVI void ins32(unsigned K, unsigned (&a)[20]){
#pragma unroll
  for (int t = 19; t >= 1; --t) a[t] = umin32(a[t], umax32(a[t-1], K));
  a[0] = umin32(a[0], K);
}
DEVI void ins64(double K, double (&a)[20]){
#pragma unroll
  for (int t = 19; t >= 1; --t) a[t] = fmin(a[t], fmax(a[t-1], K));
  a[0] = fmin(a[0], K);
}

// ---- prep: pack pos into bf16 hi/lo fragments [pt][8]=(x,y,z,0..) + |p|^2 ----
__global__ __launch_bounds__(256) void p3_k(const float* __restrict__ pos,
    unsigned short* __restrict__ p3h, unsigned short* __restrict__ p3l, float* __restrict__ nrm3){
  int p = blockIdx.x*256 + threadIdx.x;
  if (p >= NPTS) return;
  float x = pos[(size_t)p*3], y = pos[(size_t)p*3+1], z = pos[(size_t)p*3+2];
  float v[8] = {x, y, z, 0.f, 0.f, 0.f, 0.f, 0.f};
#pragma unroll
  for (int c = 0; c < 8; ++c){
    unsigned short h = f2bf(v[c]);
    p3h[(size_t)p*8 + c] = h;
    p3l[(size_t)p*8 + c] = f2bf(v[c] - bf2f(h));
  }
  nrm3[p] = fmaf(x, x, fmaf(y, y, z*z));
}

// ---- KNN: MFMA dist + u32 packed-key selection, 64 rows x 2048-cand chunk ----
// grid = 8 batches * 2 chunks * 64 rowtiles = 1024 blocks (exactly 4/CU)
// key = (distbits & ~0x7FF) | cid   (cid = local candidate id, 11 bits)
// MODE1 B tiles staged in MFMA fragment order: [nt][half][lane][8] (conflict-free imm-offset reads)
template<int MODE>
__global__ __launch_bounds__(256) void knn_k(const unsigned short* __restrict__ Xh,
                                             const unsigned short* __restrict__ Xl,
                                             const float* __restrict__ nrm,
                                             unsigned* __restrict__ pk){
  constexpr int OBL  = MODE ? 8192  : 1024;
  constexpr int OS   = MODE ? 16384 : 2048;
  constexpr int OBUF = MODE ? 33536 : 19200;
  constexpr int OSQ  = MODE ? 39680 : 25344;
  __shared__ __align__(16) char smem[MODE ? 39936 : 25600];
  unsigned short* Bh = (unsigned short*)(smem);
  unsigned short* Bl = (unsigned short*)(smem + OBL);
  unsigned* S        = (unsigned*)(smem + OS);      // [64][67] packed u32 keys
  unsigned* buf      = (unsigned*)(smem + OBUF);    // [6][256]
  float* sqj         = (float*)(smem + OSQ);        // [64]
  unsigned* mD       = (unsigned*)(smem);           // merge overlay (all dead)

  const int blk = blockIdx.x;
  const int rt = blk & 63, ch = (blk >> 6) & 1, bb = blk >> 7;
  const int rowbase = rt * 64, cbase = ch * 2048;
  const size_t gb = (size_t)bb * N_;
  const int tid = threadIdx.x, lane = tid & 63, wid = tid >> 6;
  const int l15 = lane & 15, kL = (lane >> 4) << 3, r0 = (lane >> 4) << 2;

  // A fragments direct from global (rows fixed for whole kernel)
  short8 ah0 = {0,0,0,0,0,0,0,0}, ah1 = {0,0,0,0,0,0,0,0};
  short8 al0 = {0,0,0,0,0,0,0,0}, al1 = {0,0,0,0,0,0,0,0};
  const int arow = rowbase + (wid << 4) + l15;
  if (MODE == 1){
    const size_t ab = (gb + arow) * 64;
    ah0 = *(const short8*)(Xh + ab + kL);
    ah1 = *(const short8*)(Xh + ab + 32 + kL);
    al0 = *(const short8*)(Xl + ab + kL);
    al1 = *(const short8*)(Xl + ab + 32 + kL);
  } else {
    if (lane < 16){
      const size_t ab = (gb + arow) * 8;
      ah0 = *(const short8*)(Xh + ab);
      al0 = *(const short8*)(Xl + ab);
    }
  }
  float sqi[4];
#pragma unroll
  for (int r = 0; r < 4; ++r) sqi[r] = nrm[gb + rowbase + (wid << 4) + r0 + r];

  unsigned arr[20];
#pragma unroll
  for (int t = 0; t < 20; ++t) arr[t] = 0xFFFFFFFFu;
  unsigned thrP = 0xFFFFFFFFu;
  int cnt = 0;
  const int srow = tid & 63, q = tid >> 6;

  for (int c = 0; c < 32; ++c){
    __syncthreads();
    if (MODE == 1){
      // stage in fragment order: frag f -> (nt=f>>7, half=(f>>6)&1, lane=f&63)
      for (int f = tid; f < 512; f += 256){
        int lf = f & 63, half = (f >> 6) & 1, nt = f >> 7;
        int row = nt*16 + (lf & 15);
        int col = half*32 + ((lf >> 4) << 3);
        const size_t src = (gb + cbase + c*64 + row) * 64 + col;
        *(short8*)(Bh + f*8) = *(const short8*)(Xh + src);
        *(short8*)(Bl + f*8) = *(const short8*)(Xl + src);
      }
    } else {
      if (tid < 64)       *(short8*)(Bh + tid*8)      = *(const short8*)(Xh + (gb + cbase + c*64 + tid)*8);
      else if (tid < 128) *(short8*)(Bl + (tid-64)*8) = *(const short8*)(Xl + (gb + cbase + c*64 + (tid-64))*8);
    }
    if (tid < 64) sqj[tid] = nrm[gb + cbase + c*64 + tid];
    __syncthreads();

    const bool selfTile = (cbase + c*64 == rowbase);
#pragma unroll
    for (int nt = 0; nt < 4; ++nt){
      f32x4 acc = {0.f,0.f,0.f,0.f};
      if (MODE == 1){
        const int fb = lane*8;
        short8 bh0 = *(const short8*)(Bh + (nt*2+0)*512 + fb);
        short8 bh1 = *(const short8*)(Bh + (nt*2+1)*512 + fb);
        short8 bl0 = *(const short8*)(Bl + (nt*2+0)*512 + fb);
        short8 bl1 = *(const short8*)(Bl + (nt*2+1)*512 + fb);
        acc = mfma16(ah0, bh0, acc); acc = mfma16(ah1, bh1, acc);
        acc = mfma16(ah0, bl0, acc); acc = mfma16(ah1, bl1, acc);
        acc = mfma16(al0, bh0, acc); acc = mfma16(al1, bh1, acc);
      } else {
        int br = nt*16 + l15;
        short8 bh = {0,0,0,0,0,0,0,0}, bl = {0,0,0,0,0,0,0,0};
        if (lane < 16){
          bh = *(const short8*)(Bh + br*8);
          bl = *(const short8*)(Bl + br*8);
        }
        acc = mfma16(ah0, bh, acc);
        acc = mfma16(ah0, bl, acc);
        acc = mfma16(al0, bh, acc);
      }
      int col = nt*16 + l15;
      float sj = sqj[col];
      unsigned cid = (unsigned)(c*64 + col);
#pragma unroll
      for (int r = 0; r < 4; ++r){
        int row = (wid << 4) + r0 + r;
        float dv = fmaxf(fmaf(-2.f, acc[r], sqi[r] + sj), 0.f);  // true dist >= 0
        unsigned kb = (__float_as_uint(dv) & ~0x7FFu) | cid;
        if (selfTile && col == row) kb = 0x7F800000u | cid;      // self -> +inf
        S[row*67 + col] = kb;
      }
    }
    __syncthreads();

    { // scan own 16 candidates, push survivors (conflict-free buf), flush
      const unsigned* Sr = S + srow*67 + q*16;
#pragma unroll
      for (int u = 0; u < 16; ++u){
        unsigned kb = Sr[u];
        if (kb < thrP){
          if (cnt < 6){ buf[cnt*256 + tid] = kb; ++cnt; }
          else ins32(kb, arr);
        }
      }
      for (int t = 0; t < cnt; ++t) ins32(buf[t*256 + tid], arr);
      cnt = 0;
      thrP = arr[19];
    }
  }
  __syncthreads();
  if (q > 0){
#pragma unroll
    for (int t = 0; t < 20; ++t) mD[(srow*3 + q-1)*20 + t] = arr[t];
  }
  __syncthreads();
  if (q == 0){
    for (int qq = 0; qq < 3; ++qq)
#pragma unroll
      for (int t = 0; t < 20; ++t) ins32(mD[(srow*3 + qq)*20 + t], arr);
    const size_t gp = gb + rowbase + srow;
#pragma unroll
    for (int t = 0; t < 20; ++t) pk[((size_t)(ch*20 + t))*NPTS + gp] = arr[t];
  }
}

// ---- merge 2 chunk top-20s -> final idx ----
__global__ __launch_bounds__(256) void knn_merge_k(const unsigned* __restrict__ pk,
                                                   int* __restrict__ idx){
  const int p = blockIdx.x*256 + threadIdx.x;
  double arr[20];
#pragma unroll
  for (int t = 0; t < 20; ++t){
    unsigned k = pk[(size_t)t*NPTS + p];
    unsigned long long K = (((unsigned long long)(k & ~0x7FFu)) << 1) | (k & 0x7FFu);
    arr[t] = __builtin_bit_cast(double, K);
  }
#pragma unroll
  for (int t = 0; t < 20; ++t){
    unsigned k = pk[(size_t)(20 + t)*NPTS + p];
    unsigned long long K = (((unsigned long long)(k & ~0x7FFu)) << 1) | (2048u + (k & 0x7FFu));
    ins64(__builtin_bit_cast(double, K), arr);
  }
  int* o = idx + (size_t)p*KNN_;
#pragma unroll
  for (int t = 0; t < 20; ++t)
    o[t] = (int)(__builtin_bit_cast(unsigned long long, arr[t]) & 0xFFFu);
}

// ------- weight staging into MFMA fragment order (hi/lo split optional) -------
__global__ void stage_w_k(const float* __restrict__ src, unsigned short* __restrict__ dh,
                          unsigned short* __restrict__ dl, int K, int Nw, int KT, int NT){
  int tid = blockIdx.x*256 + threadIdx.x;
  if (tid >= NT*KT*64) return;
  int l = tid & 63;
  int kk = (tid >> 6) % KT;
  int nt = tid / (64*KT);
  int n = nt*16 + (l & 15);
  int kb = kk*32 + ((l >> 4) << 3);
#pragma unroll
  for (int e=0;e<8;++e){
    int k = kb + e;
    float w = (k < K) ? src[(size_t)k*Nw + n] : 0.f;
    unsigned short h = f2bf(w);
    dh[(size_t)tid*8 + e] = h;
    if (dl) dl[(size_t)tid*8 + e] = f2bf(w - bf2f(h));
  }
}

// ------------- EdgeConv1: 6->64->64->64, hi/lo 3-split, swapped-operand MFMA -------------
// mfma(W, Act): acc[r] = (outcol = nt*16+r0+r, actrow = mt*16+l15) -> b64 H-writes
__global__ __launch_bounds__(256) void ec1_k(const float* __restrict__ pos, const int* __restrict__ idx1,
    const unsigned short* __restrict__ W1h, const unsigned short* __restrict__ W1l,
    const unsigned short* __restrict__ W2h, const unsigned short* __restrict__ W2l,
    const unsigned short* __restrict__ W3h, const unsigned short* __restrict__ W3l,
    const float* __restrict__ b1, const float* __restrict__ b2, const float* __restrict__ b3,
    unsigned short* __restrict__ x1h, unsigned short* __restrict__ x1l, float* __restrict__ nrm1){
  __shared__ __align__(16) char smem[52224];
  unsigned short* Ah  = (unsigned short*)(smem);            // [80][32]
  unsigned short* Al  = (unsigned short*)(smem + 5120);
  unsigned short* H1h = (unsigned short*)(smem + 10240);    // [80][64]
  unsigned short* H1l = (unsigned short*)(smem + 20480);
  unsigned short* H2h = (unsigned short*)(smem + 30720);
  unsigned short* H2l = (unsigned short*)(smem + 40960);
  unsigned* pmax = (unsigned*)(smem + 51200);               // [4][64]
  const int p0 = blockIdx.x * 4;
  const int bb = p0 >> 12;
  const int tid = threadIdx.x, lane = tid & 63, wid = tid >> 6;
  pmax[tid] = 0u;
  if (tid < 80){
    int p = p0 + tid/20, slot = tid%20;
    int j = idx1[(size_t)p*KNN_ + slot];
    int gj = (bb << 12) + j;
    float a6[6];
    a6[0] = pos[(size_t)p*3]; a6[1] = pos[(size_t)p*3+1]; a6[2] = pos[(size_t)p*3+2];
    a6[3] = pos[(size_t)gj*3]   - a6[0];
    a6[4] = pos[(size_t)gj*3+1] - a6[1];
    a6[5] = pos[(size_t)gj*3+2] - a6[2];
#pragma unroll
    for (int q=0;q<4;++q){
      short8 vh, vl;
#pragma unroll
      for (int c=0;c<8;++c){
        int cc = q*8+c;
        float v = 0.f;
        if (cc < 6) v = a6[cc];
        unsigned short h = f2bf(v);
        vh[c] = (short)h;
        vl[c] = (short)f2bf(v - bf2f(h));
      }
      lds_put8(Ah, tid, q*8, 32, 3, vh);
      lds_put8(Al, tid, q*8, 32, 3, vl);
    }
  }
  __syncthreads();
  const int l15 = lane & 15, kL = (lane >> 4) << 3, r0 = (lane >> 4) << 2;
  { // layer 1 (K=32 slot, 6 real)
    int nt = wid;
    short8 wh = *(const short8*)(W1h + ((size_t)nt*64 + lane)*8);
    short8 wl = *(const short8*)(W1l + ((size_t)nt*64 + lane)*8);
    f32x4 b4 = *(const f32x4*)(b1 + nt*16 + r0);
    for (int mt=0; mt<5; ++mt){
      int ar = mt*16 + l15;
      short8 ah = lds_frag(Ah, ar, kL, 32, 3);
      short8 al = lds_frag(Al, ar, kL, 32, 3);
      f32x4 acc = {0.f,0.f,0.f,0.f};
      acc = mfma16(wh, ah, acc);
      acc = mfma16(wl, ah, acc);
      acc = mfma16(wh, al, acc);
      short4v vh4, vl4;
#pragma unroll
      for (int r=0;r<4;++r){
        float v = fmaxf(acc[r] + b4[r], 0.f);
        unsigned short h = f2bf(v);
        vh4[r] = (short)h;
        vl4[r] = (short)f2bf(v - bf2f(h));
      }
      lds_put4(H1h, ar, nt*16 + r0, 64, 7, vh4);
      lds_put4(H1l, ar, nt*16 + r0, 64, 7, vl4);
    }
  }
  __syncthreads();
  { // layer 2
    int nt = wid;
    short8 wh0 = *(const short8*)(W2h + ((size_t)(nt*2+0)*64 + lane)*8);
    short8 wh1 = *(const short8*)(W2h + ((size_t)(nt*2+1)*64 + lane)*8);
    short8 wl0 = *(const short8*)(W2l + ((size_t)(nt*2+0)*64 + lane)*8);
    short8 wl1 = *(const short8*)(W2l + ((size_t)(nt*2+1)*64 + lane)*8);
    f32x4 b4 = *(const f32x4*)(b2 + nt*16 + r0);
    for (int mt=0; mt<5; ++mt){
      int ar = mt*16 + l15;
      short8 ah0 = lds_frag(H1h, ar, kL,      64, 7);
      short8 ah1 = lds_frag(H1h, ar, 32 + kL, 64, 7);
      short8 al0 = lds_frag(H1l, ar, kL,      64, 7);
      short8 al1 = lds_frag(H1l, ar, 32 + kL, 64, 7);
      f32x4 acc = {0.f,0.f,0.f,0.f};
      acc = mfma16(wh0, ah0, acc); acc = mfma16(wh1, ah1, acc);
      acc = mfma16(wl0, ah0, acc); acc = mfma16(wl1, ah1, acc);
      acc = mfma16(wh0, al0, acc); acc = mfma16(wh1, al1, acc);
      short4v vh4, vl4;
#pragma unroll
      for (int r=0;r<4;++r){
        float v = fmaxf(acc[r] + b4[r], 0.f);
        unsigned short h = f2bf(v);
        vh4[r] = (short)h;
        vl4[r] = (short)f2bf(v - bf2f(h));
      }
      lds_put4(H2h, ar, nt*16 + r0, 64, 7, vh4);
      lds_put4(H2l, ar, nt*16 + r0, 64, 7, vl4);
    }
  }
  __syncthreads();
  { // layer 3 -> atomicMax pool (relu'd >=0, uint order == float order)
    int nt = wid;
    short8 wh0 = *(const short8*)(W3h + ((size_t)(nt*2+0)*64 + lane)*8);
    short8 wh1 = *(const short8*)(W3h + ((size_t)(nt*2+1)*64 + lane)*8);
    short8 wl0 = *(const short8*)(W3l + ((size_t)(nt*2+0)*64 + lane)*8);
    short8 wl1 = *(const short8*)(W3l + ((size_t)(nt*2+1)*64 + lane)*8);
    f32x4 b4 = *(const f32x4*)(b3 + nt*16 + r0);
    for (int mt=0; mt<5; ++mt){
      int ar = mt*16 + l15;
      short8 ah0 = lds_frag(H2h, ar, kL,      64, 7);
      short8 ah1 = lds_frag(H2h, ar, 32 + kL, 64, 7);
      short8 al0 = lds_frag(H2l, ar, kL,      64, 7);
      short8 al1 = lds_frag(H2l, ar, 32 + kL, 64, 7);
      f32x4 acc = {0.f,0.f,0.f,0.f};
      acc = mfma16(wh0, ah0, acc); acc = mfma16(wh1, ah1, acc);
      acc = mfma16(wl0, ah0, acc); acc = mfma16(wl1, ah1, acc);
      acc = mfma16(wh0, al0, acc); acc = mfma16(wh1, al1, acc);
      int pidx = (ar/20)*64 + nt*16 + r0;
#pragma unroll
      for (int r=0;r<4;++r){
        float v = fmaxf(acc[r] + b4[r], 0.f);
        atomicMax(&pmax[pidx + r], __float_as_uint(v));
      }
    }
  }
  __syncthreads();
  if (tid < 128){ // hi/lo + squared norm from pooled values
    int p = tid >> 5, cp = tid & 31;
    int c0 = cp*2, c1 = c0 + 1;
    float m0 = __uint_as_float(pmax[p*64 + c0]);
    float m1 = __uint_as_float(pmax[p*64 + c1]);
    int gp = p0 + p;
    unsigned short h0 = f2bf(m0), h1v = f2bf(m1);
    x1h[(size_t)gp*64 + c0] = h0;
    x1h[(size_t)gp*64 + c1] = h1v;
    x1l[(size_t)gp*64 + c0] = f2bf(m0 - bf2f(h0));
    x1l[(size_t)gp*64 + c1] = f2bf(m1 - bf2f(h1v));
    float s = fmaf(m0, m0, m1*m1);
    s += __shfl_xor(s, 1, 32); s += __shfl_xor(s, 2, 32); s += __shfl_xor(s, 4, 32);
    s += __shfl_xor(s, 8, 32); s += __shfl_xor(s, 16, 32);
    if (cp == 0) nrm1[gp] = s;
  }
}

// ------------- EdgeConv2: 128->128->128->256, swapped-operand MFMA, atomic pooling -------------
__global__ __launch_bounds__(256) void ec2_k(const unsigned short* __restrict__ x1h, const int* __restrict__ idx2,
    const unsigned short* __restrict__ V1, const unsigned short* __restrict__ V2, const unsigned short* __restrict__ V3,
    const float* __restrict__ b1, const float* __restrict__ b2, const float* __restrict__ b3,
    unsigned short* __restrict__ x2b){
  __shared__ __align__(16) char smem[81920];
  unsigned short* A  = (unsigned short*)(smem);        // [160][128] bf16; reused as H2
  unsigned short* H1 = (unsigned short*)(smem + 40960);
  unsigned short* H2 = (unsigned short*)(smem);
  unsigned* pmax = (unsigned*)(smem + 40960);          // [8][256], overlays dead H1
  const int p0 = blockIdx.x * 8, bb = p0 >> 12;
  const int tid = threadIdx.x, lane = tid & 63, wid = tid >> 6;
  if (tid < 160){
    int p = p0 + tid/20, slot = tid%20;
    int j = idx2[(size_t)p*KNN_ + slot];
    int gj = (bb << 12) + j;
    const unsigned short* xi = x1h + (size_t)p*64;
    const unsigned short* xj = x1h + (size_t)gj*64;
#pragma unroll
    for (int q=0;q<8;++q){
      short8 vi = *(const short8*)(xi + q*8);
      short8 vj = *(const short8*)(xj + q*8);
      short8 vd;
#pragma unroll
      for (int c=0;c<8;++c) vd[c] = (short)f2bf(bf2fs(vj[c]) - bf2fs(vi[c]));
      lds_put8(A, tid, q*8,      128, 7, vi);
      lds_put8(A, tid, 64 + q*8, 128, 7, vd);
    }
  }
  __syncthreads();
  const int l15 = lane & 15, kL = (lane >> 4) << 3, r0 = (lane >> 4) << 2;
#pragma unroll
  for (int ni=0; ni<2; ++ni){ // layer 1: A -> H1
    int nt = wid*2 + ni;
    short8 w0 = *(const short8*)(V1 + ((size_t)(nt*4+0)*64 + lane)*8);
    short8 w1 = *(const short8*)(V1 + ((size_t)(nt*4+1)*64 + lane)*8);
    short8 w2 = *(const short8*)(V1 + ((size_t)(nt*4+2)*64 + lane)*8);
    short8 w3 = *(const short8*)(V1 + ((size_t)(nt*4+3)*64 + lane)*8);
    f32x4 b4 = *(const f32x4*)(b1 + nt*16 + r0);
    for (int mt=0; mt<10; ++mt){
      int ar = mt*16 + l15;
      f32x4 acc = {0.f,0.f,0.f,0.f};
      acc = mfma16(w0, lds_frag(A, ar,  0 + kL, 128, 7), acc);
      acc = mfma16(w1, lds_frag(A, ar, 32 + kL, 128, 7), acc);
      acc = mfma16(w2, lds_frag(A, ar, 64 + kL, 128, 7), acc);
      acc = mfma16(w3, lds_frag(A, ar, 96 + kL, 128, 7), acc);
      short4v v4;
#pragma unroll
      for (int r=0;r<4;++r) v4[r] = (short)f2bf(fmaxf(acc[r] + b4[r], 0.f));
      lds_put4(H1, ar, nt*16 + r0, 128, 7, v4);
    }
  }
  __syncthreads();
#pragma unroll
  for (int ni=0; ni<2; ++ni){ // layer 2: H1 -> H2 (=A region, A dead)
    int nt = wid*2 + ni;
    short8 w0 = *(const short8*)(V2 + ((size_t)(nt*4+0)*64 + lane)*8);
    short8 w1 = *(const short8*)(V2 + ((size_t)(nt*4+1)*64 + lane)*8);
    short8 w2 = *(const short8*)(V2 + ((size_t)(nt*4+2)*64 + lane)*8);
    short8 w3 = *(const short8*)(V2 + ((size_t)(nt*4+3)*64 + lane)*8);
    f32x4 b4 = *(const f32x4*)(b2 + nt*16 + r0);
    for (int mt=0; mt<10; ++mt){
      int ar = mt*16 + l15;
      f32x4 acc = {0.f,0.f,0.f,0.f};
      acc = mfma16(w0, lds_frag(H1, ar,  0 + kL, 128, 7), acc);
      acc = mfma16(w1, lds_frag(H1, ar, 32 + kL, 128, 7), acc);
      acc = mfma16(w2, lds_frag(H1, ar, 64 + kL, 128, 7), acc);
      acc = mfma16(w3, lds_frag(H1, ar, 96 + kL, 128, 7), acc);
      short4v v4;
#pragma unroll
      for (int r=0;r<4;++r) v4[r] = (short)f2bf(fmaxf(acc[r] + b4[r], 0.f));
      lds_put4(H2, ar, nt*16 + r0, 128, 7, v4);
    }
  }
  __syncthreads();
  for (int it = tid; it < 2048; it += 256) pmax[it] = 0u;   // H1 dead now
  __syncthreads();
  for (int g=0; g<4; ++g){ // layer 3: H2 -> atomicMax pool
    int nt = g*4 + wid;
    short8 w0 = *(const short8*)(V3 + ((size_t)(nt*4+0)*64 + lane)*8);
    short8 w1 = *(const short8*)(V3 + ((size_t)(nt*4+1)*64 + lane)*8);
    short8 w2 = *(const short8*)(V3 + ((size_t)(nt*4+2)*64 + lane)*8);
    short8 w3 = *(const short8*)(V3 + ((size_t)(nt*4+3)*64 + lane)*8);
    f32x4 b4 = *(const f32x4*)(b3 + nt*16 + r0);
    for (int mt=0; mt<10; ++mt){
      int ar = mt*16 + l15;
      f32x4 acc = {0.f,0.f,0.f,0.f};
      acc = mfma16(w0, lds_frag(H2, ar,  0 + kL, 128, 7), acc);
      acc = mfma16(w1, lds_frag(H2, ar, 32 + kL, 128, 7), acc);
      acc = mfma16(w2, lds_frag(H2, ar, 64 + kL, 128, 7), acc);
      acc = mfma16(w3, lds_frag(H2, ar, 96 + kL, 128, 7), acc);
      int pidx = (ar/20)*256 + nt*16 + r0;
#pragma unroll
      for (int r=0;r<4;++r){
        float v = fmaxf(acc[r] + b4[r], 0.f);
        atomicMax(&pmax[pidx + r], __float_as_uint(v));
      }
    }
  }
  __syncthreads();
  {
    int p = tid >> 5, cp = tid & 31;
    int gp = p0 + p;
#pragma unroll
    for (int k=0;k<8;++k){
      int c = cp*8 + k;
      x2b[(size_t)gp*256 + c] = f2bf(__uint_as_float(pmax[p*256 + c]));
    }
  }
}

// ------------- lin0 (256->512) + relu + segment-max into pool -------------
__global__ __launch_bounds__(256) void lin0_k(const unsigned short* __restrict__ x2b, const unsigned short* __restrict__ W0s,
                                              const float* __restrict__ b0, unsigned* __restrict__ pool){
  __shared__ __align__(16) char smem[67584];
  unsigned short* A = (unsigned short*)(smem);        // [128][256] bf16 swizzled
  unsigned* ploc = (unsigned*)(smem + 65536);
  const int blk = blockIdx.x; const size_t row0 = (size_t)blk * 128; const int bb = blk >> 5;
  const int tid = threadIdx.x, lane = tid & 63, wid = tid >> 6;
  for (int it = tid; it < 4096; it += 256){
    int row = it >> 5, q = (it & 31) << 3;
    lds_put8(A, row, q, 256, 7, *(const short8*)(x2b + (row0 + row)*256 + q));
  }
  ploc[tid] = 0u; ploc[tid+256] = 0u;
  __syncthreads();
  const int l15 = lane & 15, kL = (lane >> 4) << 3;
  short8 af[2][8];
#pragma unroll
  for (int m=0;m<2;++m)
#pragma unroll
    for (int kk=0;kk<8;++kk)
      af[m][kk] = lds_frag(A, (wid*2+m)*16 + l15, kk*32 + kL, 256, 7);
  for (int nt=0; nt<32; ++nt){
    f32x4 a0 = {0.f,0.f,0.f,0.f}, a1 = {0.f,0.f,0.f,0.f};
#pragma unroll
    for (int kk=0;kk<8;++kk){
      short8 w = *(const short8*)(W0s + ((size_t)(nt*8+kk)*64 + lane)*8);
      a0 = mfma16(af[0][kk], w, a0);
      a1 = mfma16(af[1][kk], w, a1);
    }
    int col = nt*16 + l15;
    float m = fmaxf(fmaxf(fmaxf(a0[0],a0[1]),fmaxf(a0[2],a0[3])),
                    fmaxf(fmaxf(a1[0],a1[1]),fmaxf(a1[2],a1[3])));
    m = fmaxf(m + b0[col], 0.f);
    atomicMax(&ploc[col], __float_as_uint(m));
  }
  __syncthreads();
  atomicMax(&pool[(size_t)bb*512 + tid], ploc[tid]);
  atomicMax(&pool[(size_t)bb*512 + tid + 256], ploc[tid+256]);
}

// ------------- head: lin1+relu, lin2+relu, lin3, log_softmax -------------
__global__ __launch_bounds__(256) void head_k(const unsigned* __restrict__ pool,
    const float* __restrict__ w1, const float* __restrict__ bb1,
    const float* __restrict__ w2, const float* __restrict__ bb2,
    const float* __restrict__ w3, const float* __restrict__ bb3,
    float* __restrict__ out){
  __shared__ float pl[8*512];
  __shared__ float y1[8*256];
  __shared__ float y2[8*256];
  __shared__ float lg[8*40];
  const int tid = threadIdx.x;
  for (int it = tid; it < 4096; it += 256) pl[it] = __uint_as_float(pool[it]);
  __syncthreads();
  {
    float acc[8]; float bv = bb1[tid];
#pragma unroll
    for (int r=0;r<8;++r) acc[r] = bv;
    for (int k=0;k<512;++k){
      float w = w1[(size_t)k*256 + tid];
#pragma unroll
      for (int r=0;r<8;++r) acc[r] = fmaf(pl[r*512+k], w, acc[r]);
    }
#pragma unroll
    for (int r=0;r<8;++r) y1[r*256+tid] = fmaxf(acc[r], 0.f);
  }
  __syncthreads();
  {
    float acc[8]; float bv = bb2[tid];
#pragma unroll
    for (int r=0;r<8;++r) acc[r] = bv;
    for (int k=0;k<256;++k){
      float w = w2[(size_t)k*256 + tid];
#pragma unroll
      for (int r=0;r<8;++r) acc[r] = fmaf(y1[r*256+k], w, acc[r]);
    }
#pragma unroll
    for (int r=0;r<8;++r) y2[r*256+tid] = fmaxf(acc[r], 0.f);
  }
  __syncthreads();
  if (tid < 40){
    float acc[8]; float bv = bb3[tid];
#pragma unroll
    for (int r=0;r<8;++r) acc[r] = bv;
    for (int k=0;k<256;++k){
      float w = w3[(size_t)k*40 + tid];
#pragma unroll
      for (int r=0;r<8;++r) acc[r] = fmaf(y2[r*256+k], w, acc[r]);
    }
#pragma unroll
    for (int r=0;r<8;++r) lg[r*40+tid] = acc[r];
  }
  __syncthreads();
  if (tid < 8){
    float m = -__builtin_inff();
    for (int c2=0;c2<40;++c2) m = fmaxf(m, lg[tid*40+c2]);
    float s = 0.f;
    for (int c2=0;c2<40;++c2) s += expf(lg[tid*40+c2] - m);
    float L = logf(s);
    for (int c2=0;c2<40;++c2) out[tid*40+c2] = lg[tid*40+c2] - m - L;
  }
}

extern "C" void kernel_launch(void* const* d_in, const int* in_sizes, int n_in,
                              void* d_out, int out_size, void* d_ws, size_t ws_size,
                              hipStream_t stream){
  (void)in_sizes; (void)n_in; (void)out_size; (void)ws_size;
  const float* pos  = (const float*)d_in[0];
  const float* m1w1 = (const float*)d_in[2];  const float* m1b1 = (const float*)d_in[3];
  const float* m1w2 = (const float*)d_in[4];  const float* m1b2 = (const float*)d_in[5];
  const float* m1w3 = (const float*)d_in[6];  const float* m1b3 = (const float*)d_in[7];
  const float* m2w1 = (const float*)d_in[8];  const float* m2b1 = (const float*)d_in[9];
  const float* m2w2 = (const float*)d_in[10]; const float* m2b2 = (const float*)d_in[11];
  const float* m2w3 = (const float*)d_in[12]; const float* m2b3 = (const float*)d_in[13];
  const float* l0w  = (const float*)d_in[14]; const float* l0b  = (const float*)d_in[15];
  const float* l1w  = (const float*)d_in[16]; const float* l1b  = (const float*)d_in[17];
  const float* l2w  = (const float*)d_in[18]; const float* l2b  = (const float*)d_in[19];
  const float* l3w  = (const float*)d_in[20]; const float* l3b  = (const float*)d_in[21];

  char* ws = (char*)d_ws;
  size_t o = 0;
  auto alloc = [&](size_t bytes){ size_t r = o; o += (bytes + 255) & ~(size_t)255; return r; };
  size_t o_idx1 = alloc((size_t)NPTS*20*4);
  size_t o_idx2 = alloc((size_t)NPTS*20*4);
  size_t o_x1h  = alloc((size_t)NPTS*64*2);
  size_t o_x1l  = alloc((size_t)NPTS*64*2);
  size_t o_nrm  = alloc((size_t)NPTS*4);
  size_t o_x2b  = alloc((size_t)NPTS*256*2);
  size_t o_pool = alloc(8*512*4);
  size_t o_p3h  = alloc((size_t)NPTS*8*2);
  size_t o_p3l  = alloc((size_t)NPTS*8*2);
  size_t o_nrm3 = alloc((size_t)NPTS*4);
  size_t o_pk   = alloc((size_t)2*20*NPTS*4);
  size_t o_W1h = alloc(4*1*64*8*2),  o_W1l = alloc(4*1*64*8*2);
  size_t o_W2h = alloc(4*2*64*8*2),  o_W2l = alloc(4*2*64*8*2);
  size_t o_W3h = alloc(4*2*64*8*2),  o_W3l = alloc(4*2*64*8*2);
  size_t o_V1  = alloc(8*4*64*8*2);
  size_t o_V2  = alloc(8*4*64*8*2);
  size_t o_V3  = alloc(16*4*64*8*2);
  size_t o_W0  = alloc(32*8*64*8*2);

  hipMemsetAsync(ws + o_pool, 0, 8*512*4, stream);

  stage_w_k<<<1,256,0,stream>>>(m1w1, (unsigned short*)(ws+o_W1h), (unsigned short*)(ws+o_W1l), 6, 64, 1, 4);
  stage_w_k<<<2,256,0,stream>>>(m1w2, (unsigned short*)(ws+o_W2h), (unsigned short*)(ws+o_W2l), 64, 64, 2, 4);
  stage_w_k<<<2,256,0,stream>>>(m1w3, (unsigned short*)(ws+o_W3h), (unsigned short*)(ws+o_W3l), 64, 64, 2, 4);
  stage_w_k<<<8,256,0,stream>>>(m2w1, (unsigned short*)(ws+o_V1), nullptr, 128, 128, 4, 8);
  stage_w_k<<<8,256,0,stream>>>(m2w2, (unsigned short*)(ws+o_V2), nullptr, 128, 128, 4, 8);
  stage_w_k<<<16,256,0,stream>>>(m2w3, (unsigned short*)(ws+o_V3), nullptr, 128, 256, 4, 16);
  stage_w_k<<<64,256,0,stream>>>(l0w,  (unsigned short*)(ws+o_W0), nullptr, 256, 512, 8, 32);

  p3_k<<<128,256,0,stream>>>(pos, (unsigned short*)(ws+o_p3h), (unsigned short*)(ws+o_p3l), (float*)(ws+o_nrm3));

  knn_k<0><<<1024,256,0,stream>>>((const unsigned short*)(ws+o_p3h), (const unsigned short*)(ws+o_p3l),
                                  (const float*)(ws+o_nrm3), (unsigned*)(ws+o_pk));
  knn_merge_k<<<128,256,0,stream>>>((const unsigned*)(ws+o_pk), (int*)(ws+o_idx1));

  ec1_k<<<8192,256,0,stream>>>(pos, (const int*)(ws+o_idx1),
      (const unsigned short*)(ws+o_W1h), (const unsigned short*)(ws+o_W1l),
      (const unsigned short*)(ws+o_W2h), (const unsigned short*)(ws+o_W2l),
      (const unsigned short*)(ws+o_W3h), (const unsigned short*)(ws+o_W3l),
      m1b1, m1b2, m1b3,
      (unsigned short*)(ws+o_x1h), (unsigned short*)(ws+o_x1l), (float*)(ws+o_nrm));

  knn_k<1><<<1024,256,0,stream>>>((const unsigned short*)(ws+o_x1h), (const unsigned short*)(ws+o_x1l),
                                  (const float*)(ws+o_nrm), (unsigned*)(ws+o_pk));
  knn_merge_k<<<128,256,0,stream>>>((const unsigned*)(ws+o_pk), (int*)(ws+o_idx2));

  ec2_k<<<4096,256,0,stream>>>((const unsigned short*)(ws+o_x1h), (const int*)(ws+o_idx2),
      (const unsigned short*)(ws+o_V1), (const unsigned short*)(ws+o_V2), (const unsigned short*)(ws+o_V3),
      m2b1, m2b2, m2b3, (unsigned short*)(ws+o_x2b));

  lin0_k<<<256,256,0,stream>>>((const unsigned short*)(ws+o_x2b), (const unsigned short*)(ws+o_W0),
                               l0b, (unsigned*)(ws+o_pool));

  head_k<<<1,256,0,stream>>>((const unsigned*)(ws+o_pool), l1w, l1b, l2w, l2b, l3w, l3b, (float*)d_out);
}

// Round 6
// 715.047 us; speedup vs baseline: 1.4310x; 1.4310x over previous
//
#include <hip/hip_runtime.h>

#define DEVI static __device__ __forceinline__

typedef __attribute__((ext_vector_type(4))) float f32x4;
typedef __attribute__((ext_vector_type(8))) short short8;
typedef __attribute__((ext_vector_type(4))) short short4v;
typedef __attribute__((ext_vector_type(8))) __bf16 bf16x8;

#define N_    4096
#define KNN_  20
#define NPTS  32768

DEVI unsigned short f2bf(float f){
  unsigned u = __float_as_uint(f);
  u += 0x7FFFu + ((u >> 16) & 1u);
  return (unsigned short)(u >> 16);
}
DEVI float bf2f(unsigned short s){ return __uint_as_float(((unsigned)s) << 16); }
DEVI float bf2fs(short s){ return __uint_as_float(((unsigned)(unsigned short)s) << 16); }
DEVI unsigned umin32(unsigned a, unsigned b){ return a < b ? a : b; }
DEVI unsigned umax32(unsigned a, unsigned b){ return a > b ? a : b; }

DEVI f32x4 mfma16(short8 a, short8 b, f32x4 c){
  return __builtin_amdgcn_mfma_f32_16x16x32_bf16(
      __builtin_bit_cast(bf16x8, a), __builtin_bit_cast(bf16x8, b), c, 0, 0, 0);
}

// LDS row-major bf16 tiles, XOR swizzle on 16B granules (used by ec1/lin0)
DEVI short8 lds_frag(const unsigned short* buf, int row, int k0, int strideS, int swzMask){
  return *(const short8*)(buf + row*strideS + (k0 ^ ((row & swzMask) << 3)));
}
DEVI void lds_put8(unsigned short* buf, int row, int k0, int strideS, int swzMask, short8 v){
  *(short8*)(buf + row*strideS + (k0 ^ ((row & swzMask) << 3))) = v;
}
DEVI void lds_put1(unsigned short* buf, int row, int col, int strideS, int swzMask, unsigned short v){
  buf[row*strideS + (col ^ ((row & swzMask) << 3))] = v;
}

// blind sorted-insert into ascending top-20 (min/max identity, no-op if K>=a[19])
DEVI void ins32(unsigned K, unsigned (&a)[20]){
#pragma unroll
  for (int t = 19; t >= 1; --t) a[t] = umin32(a[t], umax32(a[t-1], K));
  a[0] = umin32(a[0], K);
}
DEVI void ins64(double K, double (&a)[20]){
#pragma unroll
  for (int t = 19; t >= 1; --t) a[t] = fmin(a[t], fmax(a[t-1], K));
  a[0] = fmin(a[0], K);
}

// ---- prep: pack pos into bf16 hi/lo fragments [pt][8]=(x,y,z,0..) + |p|^2 ----
__global__ __launch_bounds__(256) void p3_k(const float* __restrict__ pos,
    unsigned short* __restrict__ p3h, unsigned short* __restrict__ p3l, float* __restrict__ nrm3){
  int p = blockIdx.x*256 + threadIdx.x;
  if (p >= NPTS) return;
  float x = pos[(size_t)p*3], y = pos[(size_t)p*3+1], z = pos[(size_t)p*3+2];
  float v[8] = {x, y, z, 0.f, 0.f, 0.f, 0.f, 0.f};
#pragma unroll
  for (int c = 0; c < 8; ++c){
    unsigned short h = f2bf(v[c]);
    p3h[(size_t)p*8 + c] = h;
    p3l[(size_t)p*8 + c] = f2bf(v[c] - bf2f(h));
  }
  nrm3[p] = fmaf(x, x, fmaf(y, y, z*z));
}

// ---- KNN: MFMA dist + u32 packed-key selection, 64 rows x 2048-cand chunk ----
template<int MODE>
__global__ __launch_bounds__(256) void knn_k(const unsigned short* __restrict__ Xh,
                                             const unsigned short* __restrict__ Xl,
                                             const float* __restrict__ nrm,
                                             unsigned* __restrict__ pk){
  constexpr int OBL  = MODE ? 8192  : 1024;
  constexpr int OS   = MODE ? 16384 : 2048;
  constexpr int OBUF = MODE ? 33536 : 19200;
  constexpr int OSQ  = MODE ? 39680 : 25344;
  __shared__ __align__(16) char smem[MODE ? 39936 : 25600];
  unsigned short* Bh = (unsigned short*)(smem);
  unsigned short* Bl = (unsigned short*)(smem + OBL);
  unsigned* S        = (unsigned*)(smem + OS);      // [64][67] packed u32 keys
  unsigned* buf      = (unsigned*)(smem + OBUF);    // [6][256]
  float* sqj         = (float*)(smem + OSQ);        // [64]
  unsigned* mD       = (unsigned*)(smem);           // merge overlay (all dead)

  const int blk = blockIdx.x;
  const int rt = blk & 63, ch = (blk >> 6) & 1, bb = blk >> 7;
  const int rowbase = rt * 64, cbase = ch * 2048;
  const size_t gb = (size_t)bb * N_;
  const int tid = threadIdx.x, lane = tid & 63, wid = tid >> 6;
  const int l15 = lane & 15, kL = (lane >> 4) << 3, r0 = (lane >> 4) << 2;

  short8 ah0 = {0,0,0,0,0,0,0,0}, ah1 = {0,0,0,0,0,0,0,0};
  short8 al0 = {0,0,0,0,0,0,0,0}, al1 = {0,0,0,0,0,0,0,0};
  const int arow = rowbase + (wid << 4) + l15;
  if (MODE == 1){
    const size_t ab = (gb + arow) * 64;
    ah0 = *(const short8*)(Xh + ab + kL);
    ah1 = *(const short8*)(Xh + ab + 32 + kL);
    al0 = *(const short8*)(Xl + ab + kL);
    al1 = *(const short8*)(Xl + ab + 32 + kL);
  } else {
    if (lane < 16){
      const size_t ab = (gb + arow) * 8;
      ah0 = *(const short8*)(Xh + ab);
      al0 = *(const short8*)(Xl + ab);
    }
  }
  float sqi[4];
#pragma unroll
  for (int r = 0; r < 4; ++r) sqi[r] = nrm[gb + rowbase + (wid << 4) + r0 + r];

  unsigned arr[20];
#pragma unroll
  for (int t = 0; t < 20; ++t) arr[t] = 0xFFFFFFFFu;
  unsigned thrP = 0xFFFFFFFFu;
  int cnt = 0;
  const int srow = tid & 63, q = tid >> 6;

  for (int c = 0; c < 32; ++c){
    __syncthreads();
    if (MODE == 1){
      for (int f = tid; f < 512; f += 256){
        int lf = f & 63, half = (f >> 6) & 1, nt = f >> 7;
        int row = nt*16 + (lf & 15);
        int col = half*32 + ((lf >> 4) << 3);
        const size_t src = (gb + cbase + c*64 + row) * 64 + col;
        *(short8*)(Bh + f*8) = *(const short8*)(Xh + src);
        *(short8*)(Bl + f*8) = *(const short8*)(Xl + src);
      }
    } else {
      if (tid < 64)       *(short8*)(Bh + tid*8)      = *(const short8*)(Xh + (gb + cbase + c*64 + tid)*8);
      else if (tid < 128) *(short8*)(Bl + (tid-64)*8) = *(const short8*)(Xl + (gb + cbase + c*64 + (tid-64))*8);
    }
    if (tid < 64) sqj[tid] = nrm[gb + cbase + c*64 + tid];
    __syncthreads();

    const bool selfTile = (cbase + c*64 == rowbase);
#pragma unroll
    for (int nt = 0; nt < 4; ++nt){
      f32x4 acc = {0.f,0.f,0.f,0.f};
      if (MODE == 1){
        const int fb = lane*8;
        short8 bh0 = *(const short8*)(Bh + (nt*2+0)*512 + fb);
        short8 bh1 = *(const short8*)(Bh + (nt*2+1)*512 + fb);
        short8 bl0 = *(const short8*)(Bl + (nt*2+0)*512 + fb);
        short8 bl1 = *(const short8*)(Bl + (nt*2+1)*512 + fb);
        acc = mfma16(ah0, bh0, acc); acc = mfma16(ah1, bh1, acc);
        acc = mfma16(ah0, bl0, acc); acc = mfma16(ah1, bl1, acc);
        acc = mfma16(al0, bh0, acc); acc = mfma16(al1, bh1, acc);
      } else {
        int br = nt*16 + l15;
        short8 bh = {0,0,0,0,0,0,0,0}, bl = {0,0,0,0,0,0,0,0};
        if (lane < 16){
          bh = *(const short8*)(Bh + br*8);
          bl = *(const short8*)(Bl + br*8);
        }
        acc = mfma16(ah0, bh, acc);
        acc = mfma16(ah0, bl, acc);
        acc = mfma16(al0, bh, acc);
      }
      int col = nt*16 + l15;
      float sj = sqj[col];
      unsigned cid = (unsigned)(c*64 + col);
#pragma unroll
      for (int r = 0; r < 4; ++r){
        int row = (wid << 4) + r0 + r;
        float dv = fmaxf(fmaf(-2.f, acc[r], sqi[r] + sj), 0.f);
        unsigned kb = (__float_as_uint(dv) & ~0x7FFu) | cid;
        if (selfTile && col == row) kb = 0x7F800000u | cid;
        S[row*67 + col] = kb;
      }
    }
    __syncthreads();

    {
      const unsigned* Sr = S + srow*67 + q*16;
#pragma unroll
      for (int u = 0; u < 16; ++u){
        unsigned kb = Sr[u];
        if (kb < thrP){
          if (cnt < 6){ buf[cnt*256 + tid] = kb; ++cnt; }
          else ins32(kb, arr);
        }
      }
      for (int t = 0; t < cnt; ++t) ins32(buf[t*256 + tid], arr);
      cnt = 0;
      thrP = arr[19];
    }
  }
  __syncthreads();
  if (q > 0){
#pragma unroll
    for (int t = 0; t < 20; ++t) mD[(srow*3 + q-1)*20 + t] = arr[t];
  }
  __syncthreads();
  if (q == 0){
    for (int qq = 0; qq < 3; ++qq)
#pragma unroll
      for (int t = 0; t < 20; ++t) ins32(mD[(srow*3 + qq)*20 + t], arr);
    const size_t gp = gb + rowbase + srow;
#pragma unroll
    for (int t = 0; t < 20; ++t) pk[((size_t)(ch*20 + t))*NPTS + gp] = arr[t];
  }
}

// ---- merge 2 chunk top-20s -> final idx ----
__global__ __launch_bounds__(256) void knn_merge_k(const unsigned* __restrict__ pk,
                                                   int* __restrict__ idx){
  const int p = blockIdx.x*256 + threadIdx.x;
  double arr[20];
#pragma unroll
  for (int t = 0; t < 20; ++t){
    unsigned k = pk[(size_t)t*NPTS + p];
    unsigned long long K = (((unsigned long long)(k & ~0x7FFu)) << 1) | (k & 0x7FFu);
    arr[t] = __builtin_bit_cast(double, K);
  }
#pragma unroll
  for (int t = 0; t < 20; ++t){
    unsigned k = pk[(size_t)(20 + t)*NPTS + p];
    unsigned long long K = (((unsigned long long)(k & ~0x7FFu)) << 1) | (2048u + (k & 0x7FFu));
    ins64(__builtin_bit_cast(double, K), arr);
  }
  int* o = idx + (size_t)p*KNN_;
#pragma unroll
  for (int t = 0; t < 20; ++t)
    o[t] = (int)(__builtin_bit_cast(unsigned long long, arr[t]) & 0xFFFu);
}

// ------- weight staging into MFMA fragment order (hi/lo split optional) -------
__global__ void stage_w_k(const float* __restrict__ src, unsigned short* __restrict__ dh,
                          unsigned short* __restrict__ dl, int K, int Nw, int KT, int NT){
  int tid = blockIdx.x*256 + threadIdx.x;
  if (tid >= NT*KT*64) return;
  int l = tid & 63;
  int kk = (tid >> 6) % KT;
  int nt = tid / (64*KT);
  int n = nt*16 + (l & 15);
  int kb = kk*32 + ((l >> 4) << 3);
#pragma unroll
  for (int e=0;e<8;++e){
    int k = kb + e;
    float w = (k < K) ? src[(size_t)k*Nw + n] : 0.f;
    unsigned short h = f2bf(w);
    dh[(size_t)tid*8 + e] = h;
    if (dl) dl[(size_t)tid*8 + e] = f2bf(w - bf2f(h));
  }
}

// ------------- EdgeConv1 (round-4 version): 6->64->64->64, hi/lo 3-split -------------
__global__ __launch_bounds__(256) void ec1_k(const float* __restrict__ pos, const int* __restrict__ idx1,
    const unsigned short* __restrict__ W1h, const unsigned short* __restrict__ W1l,
    const unsigned short* __restrict__ W2h, const unsigned short* __restrict__ W2l,
    const unsigned short* __restrict__ W3h, const unsigned short* __restrict__ W3l,
    const float* __restrict__ b1, const float* __restrict__ b2, const float* __restrict__ b3,
    unsigned short* __restrict__ x1h, unsigned short* __restrict__ x1l, float* __restrict__ nrm1){
  __shared__ __align__(16) char smem[52224];
  unsigned short* Ah  = (unsigned short*)(smem);            // [80][32]
  unsigned short* Al  = (unsigned short*)(smem + 5120);
  unsigned short* H1h = (unsigned short*)(smem + 10240);    // [80][64]
  unsigned short* H1l = (unsigned short*)(smem + 20480);
  unsigned short* H2h = (unsigned short*)(smem + 30720);
  unsigned short* H2l = (unsigned short*)(smem + 40960);
  unsigned* pmax = (unsigned*)(smem + 51200);               // [4][64]
  const int p0 = blockIdx.x * 4;
  const int bb = p0 >> 12;
  const int tid = threadIdx.x, lane = tid & 63, wid = tid >> 6;
  pmax[tid] = 0u;
  if (tid < 80){
    int p = p0 + tid/20, slot = tid%20;
    int j = idx1[(size_t)p*KNN_ + slot];
    int gj = (bb << 12) + j;
    float a6[6];
    a6[0] = pos[(size_t)p*3]; a6[1] = pos[(size_t)p*3+1]; a6[2] = pos[(size_t)p*3+2];
    a6[3] = pos[(size_t)gj*3]   - a6[0];
    a6[4] = pos[(size_t)gj*3+1] - a6[1];
    a6[5] = pos[(size_t)gj*3+2] - a6[2];
#pragma unroll
    for (int q=0;q<4;++q){
      short8 vh, vl;
#pragma unroll
      for (int c=0;c<8;++c){
        int cc = q*8+c;
        float v = 0.f;
        if (cc < 6) v = a6[cc];
        unsigned short h = f2bf(v);
        vh[c] = (short)h;
        vl[c] = (short)f2bf(v - bf2f(h));
      }
      lds_put8(Ah, tid, q*8, 32, 3, vh);
      lds_put8(Al, tid, q*8, 32, 3, vl);
    }
  }
  __syncthreads();
  const int l15 = lane & 15, kL = (lane >> 4) << 3, r0 = (lane >> 4) << 2;
  { // layer 1 (K=32 slot, 6 real)
    int nt = wid;
    short8 wh = *(const short8*)(W1h + ((size_t)nt*64 + lane)*8);
    short8 wl = *(const short8*)(W1l + ((size_t)nt*64 + lane)*8);
    float bias = b1[nt*16 + l15];
    for (int mt=0; mt<5; ++mt){
      int ar = mt*16 + l15;
      short8 ah = lds_frag(Ah, ar, kL, 32, 3);
      short8 al = lds_frag(Al, ar, kL, 32, 3);
      f32x4 acc = {0.f,0.f,0.f,0.f};
      acc = mfma16(ah, wh, acc);
      acc = mfma16(ah, wl, acc);
      acc = mfma16(al, wh, acc);
#pragma unroll
      for (int r=0;r<4;++r){
        int row = mt*16 + r0 + r;
        float v = fmaxf(acc[r] + bias, 0.f);
        unsigned short h = f2bf(v);
        lds_put1(H1h, row, nt*16+l15, 64, 7, h);
        lds_put1(H1l, row, nt*16+l15, 64, 7, f2bf(v - bf2f(h)));
      }
    }
  }
  __syncthreads();
  { // layer 2
    int nt = wid;
    short8 wh0 = *(const short8*)(W2h + ((size_t)(nt*2+0)*64 + lane)*8);
    short8 wh1 = *(const short8*)(W2h + ((size_t)(nt*2+1)*64 + lane)*8);
    short8 wl0 = *(const short8*)(W2l + ((size_t)(nt*2+0)*64 + lane)*8);
    short8 wl1 = *(const short8*)(W2l + ((size_t)(nt*2+1)*64 + lane)*8);
    float bias = b2[nt*16 + l15];
    for (int mt=0; mt<5; ++mt){
      int ar = mt*16 + l15;
      short8 ah0 = lds_frag(H1h, ar, kL,      64, 7);
      short8 ah1 = lds_frag(H1h, ar, 32 + kL, 64, 7);
      short8 al0 = lds_frag(H1l, ar, kL,      64, 7);
      short8 al1 = lds_frag(H1l, ar, 32 + kL, 64, 7);
      f32x4 acc = {0.f,0.f,0.f,0.f};
      acc = mfma16(ah0, wh0, acc); acc = mfma16(ah1, wh1, acc);
      acc = mfma16(ah0, wl0, acc); acc = mfma16(ah1, wl1, acc);
      acc = mfma16(al0, wh0, acc); acc = mfma16(al1, wh1, acc);
#pragma unroll
      for (int r=0;r<4;++r){
        int row = mt*16 + r0 + r;
        float v = fmaxf(acc[r] + bias, 0.f);
        unsigned short h = f2bf(v);
        lds_put1(H2h, row, nt*16+l15, 64, 7, h);
        lds_put1(H2l, row, nt*16+l15, 64, 7, f2bf(v - bf2f(h)));
      }
    }
  }
  __syncthreads();
  { // layer 3 -> atomicMax pool (relu'd >=0, uint order == float order)
    int nt = wid;
    short8 wh0 = *(const short8*)(W3h + ((size_t)(nt*2+0)*64 + lane)*8);
    short8 wh1 = *(const short8*)(W3h + ((size_t)(nt*2+1)*64 + lane)*8);
    short8 wl0 = *(const short8*)(W3l + ((size_t)(nt*2+0)*64 + lane)*8);
    short8 wl1 = *(const short8*)(W3l + ((size_t)(nt*2+1)*64 + lane)*8);
    float bias = b3[nt*16 + l15];
    for (int mt=0; mt<5; ++mt){
      int ar = mt*16 + l15;
      short8 ah0 = lds_frag(H2h, ar, kL,      64, 7);
      short8 ah1 = lds_frag(H2h, ar, 32 + kL, 64, 7);
      short8 al0 = lds_frag(H2l, ar, kL,      64, 7);
      short8 al1 = lds_frag(H2l, ar, 32 + kL, 64, 7);
      f32x4 acc = {0.f,0.f,0.f,0.f};
      acc = mfma16(ah0, wh0, acc); acc = mfma16(ah1, wh1, acc);
      acc = mfma16(ah0, wl0, acc); acc = mfma16(ah1, wl1, acc);
      acc = mfma16(al0, wh0, acc); acc = mfma16(al1, wh1, acc);
#pragma unroll
      for (int r=0;r<4;++r){
        int row = mt*16 + r0 + r;
        float v = fmaxf(acc[r] + bias, 0.f);
        atomicMax(&pmax[(row/20)*64 + nt*16 + l15], __float_as_uint(v));
      }
    }
  }
  __syncthreads();
  if (tid < 128){ // hi/lo + squared norm from pooled values
    int p = tid >> 5, cp = tid & 31;
    int c0 = cp*2, c1 = c0 + 1;
    float m0 = __uint_as_float(pmax[p*64 + c0]);
    float m1 = __uint_as_float(pmax[p*64 + c1]);
    int gp = p0 + p;
    unsigned short h0 = f2bf(m0), h1v = f2bf(m1);
    x1h[(size_t)gp*64 + c0] = h0;
    x1h[(size_t)gp*64 + c1] = h1v;
    x1l[(size_t)gp*64 + c0] = f2bf(m0 - bf2f(h0));
    x1l[(size_t)gp*64 + c1] = f2bf(m1 - bf2f(h1v));
    float s = fmaf(m0, m0, m1*m1);
    s += __shfl_xor(s, 1, 32); s += __shfl_xor(s, 2, 32); s += __shfl_xor(s, 4, 32);
    s += __shfl_xor(s, 8, 32); s += __shfl_xor(s, 16, 32);
    if (cp == 0) nrm1[gp] = s;
  }
}

// ------------- EdgeConv2: fragment-ordered LDS, swapped-operand MFMA -------------
// All tiles in MFMA fragment order [mt][kk][lane][8]: reads = base + lane*16 (conflict-free)
// mfma(W, Act): lane holds (point = lane&15, channels nt*16 + r0 + 0..3)
__global__ __launch_bounds__(256) void ec2_k(const unsigned short* __restrict__ x1h, const int* __restrict__ idx2,
    const unsigned short* __restrict__ V1, const unsigned short* __restrict__ V2, const unsigned short* __restrict__ V3,
    const float* __restrict__ b1, const float* __restrict__ b2, const float* __restrict__ b3,
    unsigned short* __restrict__ x2b){
  __shared__ __align__(16) char smem[81920];
  unsigned short* A  = (unsigned short*)(smem);          // frag [10][4][64][8] 40KB; reused as H2
  unsigned short* H1 = (unsigned short*)(smem + 40960);  // frag 40KB; reused as layer-3 dump
  const int p0 = blockIdx.x * 8, bb = p0 >> 12;
  const int tid = threadIdx.x, lane = tid & 63, wid = tid >> 6;
  const int l15 = lane & 15, r0 = (lane >> 4) << 2;

  if (tid < 160){ // stage edge features in fragment order
    int p = p0 + tid/20, slot = tid%20;
    int j = idx2[(size_t)p*KNN_ + slot];
    int gj = (bb << 12) + j;
    const unsigned short* xi = x1h + (size_t)p*64;
    const unsigned short* xj = x1h + (size_t)gj*64;
    int mt = tid >> 4, lrow = tid & 15;
#pragma unroll
    for (int q=0;q<8;++q){
      short8 vi = *(const short8*)(xi + q*8);
      short8 vj = *(const short8*)(xj + q*8);
      short8 vd;
#pragma unroll
      for (int c=0;c<8;++c) vd[c] = (short)f2bf(bf2fs(vj[c]) - bf2fs(vi[c]));
      // channels q*8 (xi) -> kk=q>>2, sub=q&3 ; channels 64+q*8 (diff) -> kk=2+(q>>2)
      *(short8*)(A + (((mt*4 + (q>>2))*64) + (q&3)*16 + lrow)*8) = vi;
      *(short8*)(A + (((mt*4 + 2 + (q>>2))*64) + (q&3)*16 + lrow)*8) = vd;
    }
  }
  __syncthreads();

  { // layer 1: A -> H1
    short8 w[2][4];
#pragma unroll
    for (int ni=0;ni<2;++ni)
#pragma unroll
      for (int kk=0;kk<4;++kk)
        w[ni][kk] = *(const short8*)(V1 + ((size_t)((wid*2+ni)*4+kk)*64 + lane)*8);
    f32x4 b4[2];
    b4[0] = *(const f32x4*)(b1 + (wid*2+0)*16 + r0);
    b4[1] = *(const f32x4*)(b1 + (wid*2+1)*16 + r0);
    for (int mt=0; mt<10; ++mt){
      short8 bfr[4];
#pragma unroll
      for (int kk=0;kk<4;++kk) bfr[kk] = *(const short8*)(A + ((mt*4+kk)*64 + lane)*8);
#pragma unroll
      for (int ni=0;ni<2;++ni){
        int nt = wid*2 + ni;
        f32x4 acc = {0.f,0.f,0.f,0.f};
#pragma unroll
        for (int kk=0;kk<4;++kk) acc = mfma16(w[ni][kk], bfr[kk], acc);
        short4v v4;
#pragma unroll
        for (int r=0;r<4;++r) v4[r] = (short)f2bf(fmaxf(acc[r] + b4[ni][r], 0.f));
        int kk2 = nt >> 1, sub2 = (nt & 1)*2 + (r0 >> 3);
        *(short4v*)(H1 + ((mt*4+kk2)*64 + sub2*16 + l15)*8 + (r0 & 4)) = v4;
      }
    }
  }
  __syncthreads();
  { // layer 2: H1 -> H2 (=A region)
    short8 w[2][4];
#pragma unroll
    for (int ni=0;ni<2;++ni)
#pragma unroll
      for (int kk=0;kk<4;++kk)
        w[ni][kk] = *(const short8*)(V2 + ((size_t)((wid*2+ni)*4+kk)*64 + lane)*8);
    f32x4 b4[2];
    b4[0] = *(const f32x4*)(b2 + (wid*2+0)*16 + r0);
    b4[1] = *(const f32x4*)(b2 + (wid*2+1)*16 + r0);
    for (int mt=0; mt<10; ++mt){
      short8 bfr[4];
#pragma unroll
      for (int kk=0;kk<4;++kk) bfr[kk] = *(const short8*)(H1 + ((mt*4+kk)*64 + lane)*8);
#pragma unroll
      for (int ni=0;ni<2;++ni){
        int nt = wid*2 + ni;
        f32x4 acc = {0.f,0.f,0.f,0.f};
#pragma unroll
        for (int kk=0;kk<4;++kk) acc = mfma16(w[ni][kk], bfr[kk], acc);
        short4v v4;
#pragma unroll
        for (int r=0;r<4;++r) v4[r] = (short)f2bf(fmaxf(acc[r] + b4[ni][r], 0.f));
        int kk2 = nt >> 1, sub2 = (nt & 1)*2 + (r0 >> 3);
        *(short4v*)(A + ((mt*4+kk2)*64 + sub2*16 + l15)*8 + (r0 & 4)) = v4;
      }
    }
  }
  __syncthreads();
  // layer 3 in 2 channel-halves: H2(=A) -> dump(=H1) -> pooled x2b
  for (int g2=0; g2<2; ++g2){
    {
      short8 w[2][4];
#pragma unroll
      for (int ni=0;ni<2;++ni)
#pragma unroll
        for (int kk=0;kk<4;++kk)
          w[ni][kk] = *(const short8*)(V3 + ((size_t)((g2*8 + wid*2+ni)*4+kk)*64 + lane)*8);
      f32x4 b4[2];
      b4[0] = *(const f32x4*)(b3 + (g2*8 + wid*2+0)*16 + r0);
      b4[1] = *(const f32x4*)(b3 + (g2*8 + wid*2+1)*16 + r0);
      for (int mt=0; mt<10; ++mt){
        short8 bfr[4];
#pragma unroll
        for (int kk=0;kk<4;++kk) bfr[kk] = *(const short8*)(A + ((mt*4+kk)*64 + lane)*8);
#pragma unroll
        for (int ni=0;ni<2;++ni){
          int ntl = wid*2 + ni;  // local tile within the 128-ch half
          f32x4 acc = {0.f,0.f,0.f,0.f};
#pragma unroll
          for (int kk=0;kk<4;++kk) acc = mfma16(w[ni][kk], bfr[kk], acc);
          short4v v4;
#pragma unroll
          for (int r=0;r<4;++r) v4[r] = (short)f2bf(fmaxf(acc[r] + b4[ni][r], 0.f));
          int kk2 = ntl >> 1, sub2 = (ntl & 1)*2 + (r0 >> 3);
          *(short4v*)(H1 + ((mt*4+kk2)*64 + sub2*16 + l15)*8 + (r0 & 4)) = v4;
        }
      }
    }
    __syncthreads();
    if (tid < 128){ // pool: thread = (point p, 8-channel group c8); stagger rows for banks
      int p = tid >> 4, c8 = tid & 15;
      int kk = c8 >> 2, sub = c8 & 3;
      unsigned short mx[8];
#pragma unroll
      for (int e=0;e<8;++e) mx[e] = 0;
      for (int e=0;e<20;++e){
        int ee = e + p + c8; ee -= (ee >= 20) ? 20 : 0; ee -= (ee >= 20) ? 20 : 0;
        int row = p*20 + ee;
        short8 v = *(const short8*)(H1 + (((row>>4)*4 + kk)*64 + sub*16 + (row & 15))*8);
#pragma unroll
        for (int k2=0;k2<8;++k2){
          unsigned short u = (unsigned short)v[k2];
          mx[k2] = u > mx[k2] ? u : mx[k2];
        }
      }
      short8 o;
#pragma unroll
      for (int k2=0;k2<8;++k2) o[k2] = (short)mx[k2];
      *(short8*)(x2b + (size_t)(p0 + p)*256 + g2*128 + c8*8) = o;
    }
    __syncthreads();
  }
}

// ------------- lin0 (256->512) + relu + segment-max into pool -------------
__global__ __launch_bounds__(256) void lin0_k(const unsigned short* __restrict__ x2b, const unsigned short* __restrict__ W0s,
                                              const float* __restrict__ b0, unsigned* __restrict__ pool){
  __shared__ __align__(16) char smem[67584];
  unsigned short* A = (unsigned short*)(smem);        // [128][256] bf16 swizzled
  unsigned* ploc = (unsigned*)(smem + 65536);
  const int blk = blockIdx.x; const size_t row0 = (size_t)blk * 128; const int bb = blk >> 5;
  const int tid = threadIdx.x, lane = tid & 63, wid = tid >> 6;
  for (int it = tid; it < 4096; it += 256){
    int row = it >> 5, q = (it & 31) << 3;
    lds_put8(A, row, q, 256, 7, *(const short8*)(x2b + (row0 + row)*256 + q));
  }
  ploc[tid] = 0u; ploc[tid+256] = 0u;
  __syncthreads();
  const int l15 = lane & 15, kL = (lane >> 4) << 3;
  short8 af[2][8];
#pragma unroll
  for (int m=0;m<2;++m)
#pragma unroll
    for (int kk=0;kk<8;++kk)
      af[m][kk] = lds_frag(A, (wid*2+m)*16 + l15, kk*32 + kL, 256, 7);
  for (int nt=0; nt<32; ++nt){
    f32x4 a0 = {0.f,0.f,0.f,0.f}, a1 = {0.f,0.f,0.f,0.f};
#pragma unroll
    for (int kk=0;kk<8;++kk){
      short8 w = *(const short8*)(W0s + ((size_t)(nt*8+kk)*64 + lane)*8);
      a0 = mfma16(af[0][kk], w, a0);
      a1 = mfma16(af[1][kk], w, a1);
    }
    int col = nt*16 + l15;
    float m = fmaxf(fmaxf(fmaxf(a0[0],a0[1]),fmaxf(a0[2],a0[3])),
                    fmaxf(fmaxf(a1[0],a1[1]),fmaxf(a1[2],a1[3])));
    m = fmaxf(m + b0[col], 0.f);
    atomicMax(&ploc[col], __float_as_uint(m));
  }
  __syncthreads();
  atomicMax(&pool[(size_t)bb*512 + tid], ploc[tid]);
  atomicMax(&pool[(size_t)bb*512 + tid + 256], ploc[tid+256]);
}

// ------------- head: lin1+relu, lin2+relu, lin3, log_softmax -------------
__global__ __launch_bounds__(256) void head_k(const unsigned* __restrict__ pool,
    const float* __restrict__ w1, const float* __restrict__ bb1,
    const float* __restrict__ w2, const float* __restrict__ bb2,
    const float* __restrict__ w3, const float* __restrict__ bb3,
    float* __restrict__ out){
  __shared__ float pl[8*512];
  __shared__ float y1[8*256];
  __shared__ float y2[8*256];
  __shared__ float lg[8*40];
  const int tid = threadIdx.x;
  for (int it = tid; it < 4096; it += 256) pl[it] = __uint_as_float(pool[it]);
  __syncthreads();
  {
    float acc[8]; float bv = bb1[tid];
#pragma unroll
    for (int r=0;r<8;++r) acc[r] = bv;
    for (int k=0;k<512;++k){
      float w = w1[(size_t)k*256 + tid];
#pragma unroll
      for (int r=0;r<8;++r) acc[r] = fmaf(pl[r*512+k], w, acc[r]);
    }
#pragma unroll
    for (int r=0;r<8;++r) y1[r*256+tid] = fmaxf(acc[r], 0.f);
  }
  __syncthreads();
  {
    float acc[8]; float bv = bb2[tid];
#pragma unroll
    for (int r=0;r<8;++r) acc[r] = bv;
    for (int k=0;k<256;++k){
      float w = w2[(size_t)k*256 + tid];
#pragma unroll
      for (int r=0;r<8;++r) acc[r] = fmaf(y1[r*256+k], w, acc[r]);
    }
#pragma unroll
    for (int r=0;r<8;++r) y2[r*256+tid] = fmaxf(acc[r], 0.f);
  }
  __syncthreads();
  if (tid < 40){
    float acc[8]; float bv = bb3[tid];
#pragma unroll
    for (int r=0;r<8;++r) acc[r] = bv;
    for (int k=0;k<256;++k){
      float w = w3[(size_t)k*40 + tid];
#pragma unroll
      for (int r=0;r<8;++r) acc[r] = fmaf(y2[r*256+k], w, acc[r]);
    }
#pragma unroll
    for (int r=0;r<8;++r) lg[r*40+tid] = acc[r];
  }
  __syncthreads();
  if (tid < 8){
    float m = -__builtin_inff();
    for (int c2=0;c2<40;++c2) m = fmaxf(m, lg[tid*40+c2]);
    float s = 0.f;
    for (int c2=0;c2<40;++c2) s += expf(lg[tid*40+c2] - m);
    float L = logf(s);
    for (int c2=0;c2<40;++c2) out[tid*40+c2] = lg[tid*40+c2] - m - L;
  }
}

extern "C" void kernel_launch(void* const* d_in, const int* in_sizes, int n_in,
                              void* d_out, int out_size, void* d_ws, size_t ws_size,
                              hipStream_t stream){
  (void)in_sizes; (void)n_in; (void)out_size; (void)ws_size;
  const float* pos  = (const float*)d_in[0];
  const float* m1w1 = (const float*)d_in[2];  const float* m1b1 = (const float*)d_in[3];
  const float* m1w2 = (const float*)d_in[4];  const float* m1b2 = (const float*)d_in[5];
  const float* m1w3 = (const float*)d_in[6];  const float* m1b3 = (const float*)d_in[7];
  const float* m2w1 = (const float*)d_in[8];  const float* m2b1 = (const float*)d_in[9];
  const float* m2w2 = (const float*)d_in[10]; const float* m2b2 = (const float*)d_in[11];
  const float* m2w3 = (const float*)d_in[12]; const float* m2b3 = (const float*)d_in[13];
  const float* l0w  = (const float*)d_in[14]; const float* l0b  = (const float*)d_in[15];
  const float* l1w  = (const float*)d_in[16]; const float* l1b  = (const float*)d_in[17];
  const float* l2w  = (const float*)d_in[18]; const float* l2b  = (const float*)d_in[19];
  const float* l3w  = (const float*)d_in[20]; const float* l3b  = (const float*)d_in[21];

  char* ws = (char*)d_ws;
  size_t o = 0;
  auto alloc = [&](size_t bytes){ size_t r = o; o += (bytes + 255) & ~(size_t)255; return r; };
  size_t o_idx1 = alloc((size_t)NPTS*20*4);
  size_t o_idx2 = alloc((size_t)NPTS*20*4);
  size_t o_x1h  = alloc((size_t)NPTS*64*2);
  size_t o_x1l  = alloc((size_t)NPTS*64*2);
  size_t o_nrm  = alloc((size_t)NPTS*4);
  size_t o_x2b  = alloc((size_t)NPTS*256*2);
  size_t o_pool = alloc(8*512*4);
  size_t o_p3h  = alloc((size_t)NPTS*8*2);
  size_t o_p3l  = alloc((size_t)NPTS*8*2);
  size_t o_nrm3 = alloc((size_t)NPTS*4);
  size_t o_pk   = alloc((size_t)2*20*NPTS*4);
  size_t o_W1h = alloc(4*1*64*8*2),  o_W1l = alloc(4*1*64*8*2);
  size_t o_W2h = alloc(4*2*64*8*2),  o_W2l = alloc(4*2*64*8*2);
  size_t o_W3h = alloc(4*2*64*8*2),  o_W3l = alloc(4*2*64*8*2);
  size_t o_V1  = alloc(8*4*64*8*2);
  size_t o_V2  = alloc(8*4*64*8*2);
  size_t o_V3  = alloc(16*4*64*8*2);
  size_t o_W0  = alloc(32*8*64*8*2);

  hipMemsetAsync(ws + o_pool, 0, 8*512*4, stream);

  stage_w_k<<<1,256,0,stream>>>(m1w1, (unsigned short*)(ws+o_W1h), (unsigned short*)(ws+o_W1l), 6, 64, 1, 4);
  stage_w_k<<<2,256,0,stream>>>(m1w2, (unsigned short*)(ws+o_W2h), (unsigned short*)(ws+o_W2l), 64, 64, 2, 4);
  stage_w_k<<<2,256,0,stream>>>(m1w3, (unsigned short*)(ws+o_W3h), (unsigned short*)(ws+o_W3l), 64, 64, 2, 4);
  stage_w_k<<<8,256,0,stream>>>(m2w1, (unsigned short*)(ws+o_V1), nullptr, 128, 128, 4, 8);
  stage_w_k<<<8,256,0,stream>>>(m2w2, (unsigned short*)(ws+o_V2), nullptr, 128, 128, 4, 8);
  stage_w_k<<<16,256,0,stream>>>(m2w3, (unsigned short*)(ws+o_V3), nullptr, 128, 256, 4, 16);
  stage_w_k<<<64,256,0,stream>>>(l0w,  (unsigned short*)(ws+o_W0), nullptr, 256, 512, 8, 32);

  p3_k<<<128,256,0,stream>>>(pos, (unsigned short*)(ws+o_p3h), (unsigned short*)(ws+o_p3l), (float*)(ws+o_nrm3));

  knn_k<0><<<1024,256,0,stream>>>((const unsigned short*)(ws+o_p3h), (const unsigned short*)(ws+o_p3l),
                                  (const float*)(ws+o_nrm3), (unsigned*)(ws+o_pk));
  knn_merge_k<<<128,256,0,stream>>>((const unsigned*)(ws+o_pk), (int*)(ws+o_idx1));

  ec1_k<<<8192,256,0,stream>>>(pos, (const int*)(ws+o_idx1),
      (const unsigned short*)(ws+o_W1h), (const unsigned short*)(ws+o_W1l),
      (const unsigned short*)(ws+o_W2h), (const unsigned short*)(ws+o_W2l),
      (const unsigned short*)(ws+o_W3h), (const unsigned short*)(ws+o_W3l),
      m1b1, m1b2, m1b3,
      (unsigned short*)(ws+o_x1h), (unsigned short*)(ws+o_x1l), (float*)(ws+o_nrm));

  knn_k<1><<<1024,256,0,stream>>>((const unsigned short*)(ws+o_x1h), (const unsigned short*)(ws+o_x1l),
                                  (const float*)(ws+o_nrm), (unsigned*)(ws+o_pk));
  knn_merge_k<<<128,256,0,stream>>>((const unsigned*)(ws+o_pk), (int*)(ws+o_idx2));

  ec2_k<<<4096,256,0,stream>>>((const unsigned short*)(ws+o_x1h), (const int*)(ws+o_idx2),
      (const unsigned short*)(ws+o_V1), (const unsigned short*)(ws+o_V2), (const unsigned short*)(ws+o_V3),
      m2b1, m2b2, m2b3, (unsigned short*)(ws+o_x2b));

  lin0_k<<<256,256,0,stream>>>((const unsigned short*)(ws+o_x2b), (const unsigned short*)(ws+o_W0),
                               l0b, (unsigned*)(ws+o_pool));

  head_k<<<1,256,0,stream>>>((const unsigned*)(ws+o_pool), l1w, l1b, l2w, l2b, l3w, l3b, (float*)d_out);
}

// Round 7
// 655.439 us; speedup vs baseline: 1.5611x; 1.0909x over previous
//
#include <hip/hip_runtime.h>

#define DEVI static __device__ __forceinline__

typedef __attribute__((ext_vector_type(4))) float f32x4;
typedef __attribute__((ext_vector_type(8))) short short8;
typedef __attribute__((ext_vector_type(4))) short short4v;
typedef __attribute__((ext_vector_type(4))) unsigned uint4v;
typedef __attribute__((ext_vector_type(8))) __bf16 bf16x8;

#define N_    4096
#define KNN_  20
#define NPTS  32768

DEVI unsigned short f2bf(float f){
  unsigned u = __float_as_uint(f);
  u += 0x7FFFu + ((u >> 16) & 1u);
  return (unsigned short)(u >> 16);
}
DEVI float bf2f(unsigned short s){ return __uint_as_float(((unsigned)s) << 16); }
DEVI float bf2fs(short s){ return __uint_as_float(((unsigned)(unsigned short)s) << 16); }
DEVI unsigned umin32(unsigned a, unsigned b){ return a < b ? a : b; }
DEVI unsigned umax32(unsigned a, unsigned b){ return a > b ? a : b; }

DEVI f32x4 mfma16(short8 a, short8 b, f32x4 c){
  return __builtin_amdgcn_mfma_f32_16x16x32_bf16(
      __builtin_bit_cast(bf16x8, a), __builtin_bit_cast(bf16x8, b), c, 0, 0, 0);
}

// LDS row-major bf16 tiles, XOR swizzle on 16B granules (used by ec1/lin0)
DEVI short8 lds_frag(const unsigned short* buf, int row, int k0, int strideS, int swzMask){
  return *(const short8*)(buf + row*strideS + (k0 ^ ((row & swzMask) << 3)));
}
DEVI void lds_put8(unsigned short* buf, int row, int k0, int strideS, int swzMask, short8 v){
  *(short8*)(buf + row*strideS + (k0 ^ ((row & swzMask) << 3))) = v;
}
DEVI void lds_put1(unsigned short* buf, int row, int col, int strideS, int swzMask, unsigned short v){
  buf[row*strideS + (col ^ ((row & swzMask) << 3))] = v;
}

// blind sorted-insert into ascending top-20 (min/max identity, no-op if K>=a[19])
DEVI void ins32(unsigned K, unsigned (&a)[20]){
#pragma unroll
  for (int t = 19; t >= 1; --t) a[t] = umin32(a[t], umax32(a[t-1], K));
  a[0] = umin32(a[0], K);
}
DEVI void ins64(double K, double (&a)[20]){
#pragma unroll
  for (int t = 19; t >= 1; --t) a[t] = fmin(a[t], fmax(a[t-1], K));
  a[0] = fmin(a[0], K);
}

// ---- prep: pack pos into bf16 hi/lo fragments [pt][8]=(x,y,z,0..) + |p|^2 ----
__global__ __launch_bounds__(256) void p3_k(const float* __restrict__ pos,
    unsigned short* __restrict__ p3h, unsigned short* __restrict__ p3l, float* __restrict__ nrm3){
  int p = blockIdx.x*256 + threadIdx.x;
  if (p >= NPTS) return;
  float x = pos[(size_t)p*3], y = pos[(size_t)p*3+1], z = pos[(size_t)p*3+2];
  float v[8] = {x, y, z, 0.f, 0.f, 0.f, 0.f, 0.f};
#pragma unroll
  for (int c = 0; c < 8; ++c){
    unsigned short h = f2bf(v[c]);
    p3h[(size_t)p*8 + c] = h;
    p3l[(size_t)p*8 + c] = f2bf(v[c] - bf2f(h));
  }
  nrm3[p] = fmaf(x, x, fmaf(y, y, z*z));
}

// ---- KNN: MFMA dist + u32 packed-key selection, async staging, shared row thr ----
// grid = 8 batches * 2 chunks * 64 rowtiles = 1024 blocks
// key = (distbits & ~0x7FF) | cid  (cid = local candidate id in chunk, 11 bits)
template<int MODE>
__global__ __launch_bounds__(256) void knn_k(const unsigned short* __restrict__ Xh,
                                             const unsigned short* __restrict__ Xl,
                                             const float* __restrict__ nrm,
                                             unsigned* __restrict__ pk){
  constexpr int OBL  = MODE ? 8192  : 1024;   // bytes of Bh
  constexpr int OS   = MODE ? 16384 : 2048;   // S start
  constexpr int OBUF = OS + 17408;            // S = [64][68] u32
  constexpr int OTHR = OBUF + 6144;           // buf = [6][256] u32
  constexpr int OSQ  = OTHR + 256;            // rowThr[64]
  __shared__ __align__(16) char smem[OSQ + 256];
  unsigned short* Bh = (unsigned short*)(smem);
  unsigned short* Bl = (unsigned short*)(smem + OBL);
  unsigned* S        = (unsigned*)(smem + OS);
  unsigned* buf      = (unsigned*)(smem + OBUF);
  unsigned* rowThr   = (unsigned*)(smem + OTHR);
  float* sqj         = (float*)(smem + OSQ);
  unsigned* mD       = (unsigned*)(smem);     // merge overlay (all dead)

  const int blk = blockIdx.x;
  const int rt = blk & 63, ch = (blk >> 6) & 1, bb = blk >> 7;
  const int rowbase = rt * 64, cbase = ch * 2048;
  const size_t gb = (size_t)bb * N_;
  const int tid = threadIdx.x, lane = tid & 63, wid = tid >> 6;
  const int l15 = lane & 15, kL = (lane >> 4) << 3, r0 = (lane >> 4) << 2;

  if (tid < 64) rowThr[tid] = 0xFFFFFFFFu;

  short8 ah0 = {0,0,0,0,0,0,0,0}, ah1 = {0,0,0,0,0,0,0,0};
  short8 al0 = {0,0,0,0,0,0,0,0}, al1 = {0,0,0,0,0,0,0,0};
  const int arow = rowbase + (wid << 4) + l15;
  if (MODE == 1){
    const size_t ab = (gb + arow) * 64;
    ah0 = *(const short8*)(Xh + ab + kL);
    ah1 = *(const short8*)(Xh + ab + 32 + kL);
    al0 = *(const short8*)(Xl + ab + kL);
    al1 = *(const short8*)(Xl + ab + 32 + kL);
  } else {
    if (lane < 16){
      const size_t ab = (gb + arow) * 8;
      ah0 = *(const short8*)(Xh + ab);
      al0 = *(const short8*)(Xl + ab);
    }
  }
  float sqi[4];
#pragma unroll
  for (int r = 0; r < 4; ++r) sqi[r] = nrm[gb + rowbase + (wid << 4) + r0 + r];

  unsigned arr[20];
#pragma unroll
  for (int t = 0; t < 20; ++t) arr[t] = 0xFFFFFFFFu;
  int cnt = 0;
  const int srow = tid & 63, q = tid >> 6;

  // prologue: stage tile 0 directly
  if (MODE == 1){
    for (int f = tid; f < 512; f += 256){
      int lf = f & 63, half = (f >> 6) & 1, nt = f >> 7;
      int row = nt*16 + (lf & 15);
      int col = half*32 + ((lf >> 4) << 3);
      const size_t src = (gb + cbase + row) * 64 + col;
      *(short8*)(Bh + f*8) = *(const short8*)(Xh + src);
      *(short8*)(Bl + f*8) = *(const short8*)(Xl + src);
    }
  } else {
    if (tid < 64)       *(short8*)(Bh + tid*8)      = *(const short8*)(Xh + (gb + cbase + tid)*8);
    else if (tid < 128) *(short8*)(Bl + (tid-64)*8) = *(const short8*)(Xl + (gb + cbase + (tid-64))*8);
  }
  if (tid < 64) sqj[tid] = nrm[gb + cbase + tid];
  __syncthreads();

  for (int c = 0; c < 32; ++c){
    const bool selfTile = (cbase + c*64 == rowbase);
    // ---- MFMA + S writes (row-major, stride 68) ----
#pragma unroll
    for (int nt = 0; nt < 4; ++nt){
      f32x4 acc = {0.f,0.f,0.f,0.f};
      if (MODE == 1){
        const int fb = lane*8;
        short8 bh0 = *(const short8*)(Bh + (nt*2+0)*512 + fb);
        short8 bh1 = *(const short8*)(Bh + (nt*2+1)*512 + fb);
        short8 bl0 = *(const short8*)(Bl + (nt*2+0)*512 + fb);
        short8 bl1 = *(const short8*)(Bl + (nt*2+1)*512 + fb);
        acc = mfma16(ah0, bh0, acc); acc = mfma16(ah1, bh1, acc);
        acc = mfma16(ah0, bl0, acc); acc = mfma16(ah1, bl1, acc);
        acc = mfma16(al0, bh0, acc); acc = mfma16(al1, bh1, acc);
      } else {
        int br = nt*16 + l15;
        short8 bh = {0,0,0,0,0,0,0,0}, bl = {0,0,0,0,0,0,0,0};
        if (lane < 16){
          bh = *(const short8*)(Bh + br*8);
          bl = *(const short8*)(Bl + br*8);
        }
        acc = mfma16(ah0, bh, acc);
        acc = mfma16(ah0, bl, acc);
        acc = mfma16(al0, bh, acc);
      }
      int col = nt*16 + l15;
      float sj = sqj[col];
      unsigned cid = (unsigned)(c*64 + col);
#pragma unroll
      for (int r = 0; r < 4; ++r){
        int row = (wid << 4) + r0 + r;
        float dv = fmaxf(fmaf(-2.f, acc[r], sqi[r] + sj), 0.f);
        unsigned kb = (__float_as_uint(dv) & ~0x7FFu) | cid;
        if (selfTile && col == row) kb = 0x7F800000u | cid;
        S[row*68 + col] = kb;
      }
    }
    // ---- issue next-tile global loads into regs (latency hidden) ----
    short8 nh0 = {0,0,0,0,0,0,0,0}, nh1 = {0,0,0,0,0,0,0,0};
    short8 nl0 = {0,0,0,0,0,0,0,0}, nl1 = {0,0,0,0,0,0,0,0};
    float nsq = 0.f;
    const bool more = (c + 1 < 32);
    if (more){
      if (MODE == 1){
#pragma unroll
        for (int ff = 0; ff < 2; ++ff){
          int f = tid + ff*256;
          int lf = f & 63, half = (f >> 6) & 1, nt = f >> 7;
          int row = nt*16 + (lf & 15);
          int col = half*32 + ((lf >> 4) << 3);
          const size_t src = (gb + cbase + (c+1)*64 + row) * 64 + col;
          if (ff == 0){ nh0 = *(const short8*)(Xh + src); nl0 = *(const short8*)(Xl + src); }
          else        { nh1 = *(const short8*)(Xh + src); nl1 = *(const short8*)(Xl + src); }
        }
      } else {
        if (tid < 64)       nh0 = *(const short8*)(Xh + (gb + cbase + (c+1)*64 + tid)*8);
        else if (tid < 128) nl0 = *(const short8*)(Xl + (gb + cbase + (c+1)*64 + (tid-64))*8);
      }
      if (tid < 64) nsq = nrm[gb + cbase + (c+1)*64 + tid];
    }
    __syncthreads();   // S complete; B[c] reads done
    // ---- write staged regs to B (overlaps scan below via scheduler) ----
    if (more){
      if (MODE == 1){
        *(short8*)(Bh + tid*8)       = nh0;
        *(short8*)(Bh + (tid+256)*8) = nh1;
        *(short8*)(Bl + tid*8)       = nl0;
        *(short8*)(Bl + (tid+256)*8) = nl1;
      } else {
        if (tid < 64)       *(short8*)(Bh + tid*8)      = nh0;
        else if (tid < 128) *(short8*)(Bl + (tid-64)*8) = nl0;
      }
      if (tid < 64) sqj[tid] = nsq;
    }
    // ---- scan own 16 candidates (b128), shared row threshold, flush ----
    {
      unsigned thrP = rowThr[srow];
      const uint4v* Sr4 = (const uint4v*)(S + srow*68 + q*16);
#pragma unroll
      for (int u4 = 0; u4 < 4; ++u4){
        uint4v v = Sr4[u4];
#pragma unroll
        for (int e = 0; e < 4; ++e){
          unsigned kb = v[e];
          if (kb < thrP){
            if (cnt < 6){ buf[cnt*256 + tid] = kb; ++cnt; }
            else ins32(kb, arr);
          }
        }
      }
      for (int t = 0; t < cnt; ++t) ins32(buf[t*256 + tid], arr);
      cnt = 0;
      atomicMin(&rowThr[srow], arr[19]);
    }
    __syncthreads();   // B[c+1] + sqj ready; rowThr published
  }
  // ---- merge 4 threads/row -> chunk top-20 ----
  if (q > 0){
#pragma unroll
    for (int t = 0; t < 20; ++t) mD[(srow*3 + q-1)*20 + t] = arr[t];
  }
  __syncthreads();
  if (q == 0){
    for (int qq = 0; qq < 3; ++qq)
#pragma unroll
      for (int t = 0; t < 20; ++t) ins32(mD[(srow*3 + qq)*20 + t], arr);
    const size_t gp = gb + rowbase + srow;
#pragma unroll
    for (int t = 0; t < 20; ++t) pk[((size_t)(ch*20 + t))*NPTS + gp] = arr[t];
  }
}

// ---- merge 2 chunk top-20s -> final idx ----
__global__ __launch_bounds__(256) void knn_merge_k(const unsigned* __restrict__ pk,
                                                   int* __restrict__ idx){
  const int p = blockIdx.x*256 + threadIdx.x;
  double arr[20];
#pragma unroll
  for (int t = 0; t < 20; ++t){
    unsigned k = pk[(size_t)t*NPTS + p];
    unsigned long long K = (((unsigned long long)(k & ~0x7FFu)) << 1) | (k & 0x7FFu);
    arr[t] = __builtin_bit_cast(double, K);
  }
#pragma unroll
  for (int t = 0; t < 20; ++t){
    unsigned k = pk[(size_t)(20 + t)*NPTS + p];
    unsigned long long K = (((unsigned long long)(k & ~0x7FFu)) << 1) | (2048u + (k & 0x7FFu));
    ins64(__builtin_bit_cast(double, K), arr);
  }
  int* o = idx + (size_t)p*KNN_;
#pragma unroll
  for (int t = 0; t < 20; ++t)
    o[t] = (int)(__builtin_bit_cast(unsigned long long, arr[t]) & 0xFFFu);
}

// ------- weight staging into MFMA fragment order (hi/lo split optional) -------
__global__ void stage_w_k(const float* __restrict__ src, unsigned short* __restrict__ dh,
                          unsigned short* __restrict__ dl, int K, int Nw, int KT, int NT){
  int tid = blockIdx.x*256 + threadIdx.x;
  if (tid >= NT*KT*64) return;
  int l = tid & 63;
  int kk = (tid >> 6) % KT;
  int nt = tid / (64*KT);
  int n = nt*16 + (l & 15);
  int kb = kk*32 + ((l >> 4) << 3);
#pragma unroll
  for (int e=0;e<8;++e){
    int k = kb + e;
    float w = (k < K) ? src[(size_t)k*Nw + n] : 0.f;
    unsigned short h = f2bf(w);
    dh[(size_t)tid*8 + e] = h;
    if (dl) dl[(size_t)tid*8 + e] = f2bf(w - bf2f(h));
  }
}

// ------------- EdgeConv1: 6->64->64->64, hi/lo 3-split, 4 pts/block -------------
__global__ __launch_bounds__(256) void ec1_k(const float* __restrict__ pos, const int* __restrict__ idx1,
    const unsigned short* __restrict__ W1h, const unsigned short* __restrict__ W1l,
    const unsigned short* __restrict__ W2h, const unsigned short* __restrict__ W2l,
    const unsigned short* __restrict__ W3h, const unsigned short* __restrict__ W3l,
    const float* __restrict__ b1, const float* __restrict__ b2, const float* __restrict__ b3,
    unsigned short* __restrict__ x1h, unsigned short* __restrict__ x1l, float* __restrict__ nrm1){
  __shared__ __align__(16) char smem[52224];
  unsigned short* Ah  = (unsigned short*)(smem);            // [80][32]
  unsigned short* Al  = (unsigned short*)(smem + 5120);
  unsigned short* H1h = (unsigned short*)(smem + 10240);    // [80][64]
  unsigned short* H1l = (unsigned short*)(smem + 20480);
  unsigned short* H2h = (unsigned short*)(smem + 30720);
  unsigned short* H2l = (unsigned short*)(smem + 40960);
  unsigned* pmax = (unsigned*)(smem + 51200);               // [4][64]
  const int p0 = blockIdx.x * 4;
  const int bb = p0 >> 12;
  const int tid = threadIdx.x, lane = tid & 63, wid = tid >> 6;
  pmax[tid] = 0u;
  if (tid < 80){
    int p = p0 + tid/20, slot = tid%20;
    int j = idx1[(size_t)p*KNN_ + slot];
    int gj = (bb << 12) + j;
    float a6[6];
    a6[0] = pos[(size_t)p*3]; a6[1] = pos[(size_t)p*3+1]; a6[2] = pos[(size_t)p*3+2];
    a6[3] = pos[(size_t)gj*3]   - a6[0];
    a6[4] = pos[(size_t)gj*3+1] - a6[1];
    a6[5] = pos[(size_t)gj*3+2] - a6[2];
#pragma unroll
    for (int q=0;q<4;++q){
      short8 vh, vl;
#pragma unroll
      for (int c=0;c<8;++c){
        int cc = q*8+c;
        float v = 0.f;
        if (cc < 6) v = a6[cc];
        unsigned short h = f2bf(v);
        vh[c] = (short)h;
        vl[c] = (short)f2bf(v - bf2f(h));
      }
      lds_put8(Ah, tid, q*8, 32, 3, vh);
      lds_put8(Al, tid, q*8, 32, 3, vl);
    }
  }
  __syncthreads();
  const int l15 = lane & 15, kL = (lane >> 4) << 3, r0 = (lane >> 4) << 2;
  { // layer 1 (K=32 slot, 6 real)
    int nt = wid;
    short8 wh = *(const short8*)(W1h + ((size_t)nt*64 + lane)*8);
    short8 wl = *(const short8*)(W1l + ((size_t)nt*64 + lane)*8);
    float bias = b1[nt*16 + l15];
    for (int mt=0; mt<5; ++mt){
      int ar = mt*16 + l15;
      short8 ah = lds_frag(Ah, ar, kL, 32, 3);
      short8 al = lds_frag(Al, ar, kL, 32, 3);
      f32x4 acc = {0.f,0.f,0.f,0.f};
      acc = mfma16(ah, wh, acc);
      acc = mfma16(ah, wl, acc);
      acc = mfma16(al, wh, acc);
#pragma unroll
      for (int r=0;r<4;++r){
        int row = mt*16 + r0 + r;
        float v = fmaxf(acc[r] + bias, 0.f);
        unsigned short h = f2bf(v);
        lds_put1(H1h, row, nt*16+l15, 64, 7, h);
        lds_put1(H1l, row, nt*16+l15, 64, 7, f2bf(v - bf2f(h)));
      }
    }
  }
  __syncthreads();
  { // layer 2
    int nt = wid;
    short8 wh0 = *(const short8*)(W2h + ((size_t)(nt*2+0)*64 + lane)*8);
    short8 wh1 = *(const short8*)(W2h + ((size_t)(nt*2+1)*64 + lane)*8);
    short8 wl0 = *(const short8*)(W2l + ((size_t)(nt*2+0)*64 + lane)*8);
    short8 wl1 = *(const short8*)(W2l + ((size_t)(nt*2+1)*64 + lane)*8);
    float bias = b2[nt*16 + l15];
    for (int mt=0; mt<5; ++mt){
      int ar = mt*16 + l15;
      short8 ah0 = lds_frag(H1h, ar, kL,      64, 7);
      short8 ah1 = lds_frag(H1h, ar, 32 + kL, 64, 7);
      short8 al0 = lds_frag(H1l, ar, kL,      64, 7);
      short8 al1 = lds_frag(H1l, ar, 32 + kL, 64, 7);
      f32x4 acc = {0.f,0.f,0.f,0.f};
      acc = mfma16(ah0, wh0, acc); acc = mfma16(ah1, wh1, acc);
      acc = mfma16(ah0, wl0, acc); acc = mfma16(ah1, wl1, acc);
      acc = mfma16(al0, wh0, acc); acc = mfma16(al1, wh1, acc);
#pragma unroll
      for (int r=0;r<4;++r){
        int row = mt*16 + r0 + r;
        float v = fmaxf(acc[r] + bias, 0.f);
        unsigned short h = f2bf(v);
        lds_put1(H2h, row, nt*16+l15, 64, 7, h);
        lds_put1(H2l, row, nt*16+l15, 64, 7, f2bf(v - bf2f(h)));
      }
    }
  }
  __syncthreads();
  { // layer 3 -> atomicMax pool (relu'd >=0, uint order == float order)
    int nt = wid;
    short8 wh0 = *(const short8*)(W3h + ((size_t)(nt*2+0)*64 + lane)*8);
    short8 wh1 = *(const short8*)(W3h + ((size_t)(nt*2+1)*64 + lane)*8);
    short8 wl0 = *(const short8*)(W3l + ((size_t)(nt*2+0)*64 + lane)*8);
    short8 wl1 = *(const short8*)(W3l + ((size_t)(nt*2+1)*64 + lane)*8);
    float bias = b3[nt*16 + l15];
    for (int mt=0; mt<5; ++mt){
      int ar = mt*16 + l15;
      short8 ah0 = lds_frag(H2h, ar, kL,      64, 7);
      short8 ah1 = lds_frag(H2h, ar, 32 + kL, 64, 7);
      short8 al0 = lds_frag(H2l, ar, kL,      64, 7);
      short8 al1 = lds_frag(H2l, ar, 32 + kL, 64, 7);
      f32x4 acc = {0.f,0.f,0.f,0.f};
      acc = mfma16(ah0, wh0, acc); acc = mfma16(ah1, wh1, acc);
      acc = mfma16(ah0, wl0, acc); acc = mfma16(ah1, wl1, acc);
      acc = mfma16(al0, wh0, acc); acc = mfma16(al1, wh1, acc);
#pragma unroll
      for (int r=0;r<4;++r){
        int row = mt*16 + r0 + r;
        float v = fmaxf(acc[r] + bias, 0.f);
        atomicMax(&pmax[(row/20)*64 + nt*16 + l15], __float_as_uint(v));
      }
    }
  }
  __syncthreads();
  if (tid < 128){ // hi/lo + squared norm from pooled values
    int p = tid >> 5, cp = tid & 31;
    int c0 = cp*2, c1 = c0 + 1;
    float m0 = __uint_as_float(pmax[p*64 + c0]);
    float m1 = __uint_as_float(pmax[p*64 + c1]);
    int gp = p0 + p;
    unsigned short h0 = f2bf(m0), h1v = f2bf(m1);
    x1h[(size_t)gp*64 + c0] = h0;
    x1h[(size_t)gp*64 + c1] = h1v;
    x1l[(size_t)gp*64 + c0] = f2bf(m0 - bf2f(h0));
    x1l[(size_t)gp*64 + c1] = f2bf(m1 - bf2f(h1v));
    float s = fmaf(m0, m0, m1*m1);
    s += __shfl_xor(s, 1, 32); s += __shfl_xor(s, 2, 32); s += __shfl_xor(s, 4, 32);
    s += __shfl_xor(s, 8, 32); s += __shfl_xor(s, 16, 32);
    if (cp == 0) nrm1[gp] = s;
  }
}

// ------------- EdgeConv2: fragment-ordered LDS, swapped-operand MFMA -------------
__global__ __launch_bounds__(256) void ec2_k(const unsigned short* __restrict__ x1h, const int* __restrict__ idx2,
    const unsigned short* __restrict__ V1, const unsigned short* __restrict__ V2, const unsigned short* __restrict__ V3,
    const float* __restrict__ b1, const float* __restrict__ b2, const float* __restrict__ b3,
    unsigned short* __restrict__ x2b){
  __shared__ __align__(16) char smem[81920];
  unsigned short* A  = (unsigned short*)(smem);          // frag [10][4][64][8] 40KB; reused as H2
  unsigned short* H1 = (unsigned short*)(smem + 40960);  // frag 40KB; reused as layer-3 dump
  const int p0 = blockIdx.x * 8, bb = p0 >> 12;
  const int tid = threadIdx.x, lane = tid & 63, wid = tid >> 6;
  const int l15 = lane & 15, r0 = (lane >> 4) << 2;

  if (tid < 160){ // stage edge features in fragment order
    int p = p0 + tid/20, slot = tid%20;
    int j = idx2[(size_t)p*KNN_ + slot];
    int gj = (bb << 12) + j;
    const unsigned short* xi = x1h + (size_t)p*64;
    const unsigned short* xj = x1h + (size_t)gj*64;
    int mt = tid >> 4, lrow = tid & 15;
#pragma unroll
    for (int q=0;q<8;++q){
      short8 vi = *(const short8*)(xi + q*8);
      short8 vj = *(const short8*)(xj + q*8);
      short8 vd;
#pragma unroll
      for (int c=0;c<8;++c) vd[c] = (short)f2bf(bf2fs(vj[c]) - bf2fs(vi[c]));
      *(short8*)(A + (((mt*4 + (q>>2))*64) + (q&3)*16 + lrow)*8) = vi;
      *(short8*)(A + (((mt*4 + 2 + (q>>2))*64) + (q&3)*16 + lrow)*8) = vd;
    }
  }
  __syncthreads();

  { // layer 1: A -> H1
    short8 w[2][4];
#pragma unroll
    for (int ni=0;ni<2;++ni)
#pragma unroll
      for (int kk=0;kk<4;++kk)
        w[ni][kk] = *(const short8*)(V1 + ((size_t)((wid*2+ni)*4+kk)*64 + lane)*8);
    f32x4 b4[2];
    b4[0] = *(const f32x4*)(b1 + (wid*2+0)*16 + r0);
    b4[1] = *(const f32x4*)(b1 + (wid*2+1)*16 + r0);
    for (int mt=0; mt<10; ++mt){
      short8 bfr[4];
#pragma unroll
      for (int kk=0;kk<4;++kk) bfr[kk] = *(const short8*)(A + ((mt*4+kk)*64 + lane)*8);
#pragma unroll
      for (int ni=0;ni<2;++ni){
        int nt = wid*2 + ni;
        f32x4 acc = {0.f,0.f,0.f,0.f};
#pragma unroll
        for (int kk=0;kk<4;++kk) acc = mfma16(w[ni][kk], bfr[kk], acc);
        short4v v4;
#pragma unroll
        for (int r=0;r<4;++r) v4[r] = (short)f2bf(fmaxf(acc[r] + b4[ni][r], 0.f));
        int kk2 = nt >> 1, sub2 = (nt & 1)*2 + (r0 >> 3);
        *(short4v*)(H1 + ((mt*4+kk2)*64 + sub2*16 + l15)*8 + (r0 & 4)) = v4;
      }
    }
  }
  __syncthreads();
  { // layer 2: H1 -> H2 (=A region)
    short8 w[2][4];
#pragma unroll
    for (int ni=0;ni<2;++ni)
#pragma unroll
      for (int kk=0;kk<4;++kk)
        w[ni][kk] = *(const short8*)(V2 + ((size_t)((wid*2+ni)*4+kk)*64 + lane)*8);
    f32x4 b4[2];
    b4[0] = *(const f32x4*)(b2 + (wid*2+0)*16 + r0);
    b4[1] = *(const f32x4*)(b2 + (wid*2+1)*16 + r0);
    for (int mt=0; mt<10; ++mt){
      short8 bfr[4];
#pragma unroll
      for (int kk=0;kk<4;++kk) bfr[kk] = *(const short8*)(H1 + ((mt*4+kk)*64 + lane)*8);
#pragma unroll
      for (int ni=0;ni<2;++ni){
        int nt = wid*2 + ni;
        f32x4 acc = {0.f,0.f,0.f,0.f};
#pragma unroll
        for (int kk=0;kk<4;++kk) acc = mfma16(w[ni][kk], bfr[kk], acc);
        short4v v4;
#pragma unroll
        for (int r=0;r<4;++r) v4[r] = (short)f2bf(fmaxf(acc[r] + b4[ni][r], 0.f));
        int kk2 = nt >> 1, sub2 = (nt & 1)*2 + (r0 >> 3);
        *(short4v*)(A + ((mt*4+kk2)*64 + sub2*16 + l15)*8 + (r0 & 4)) = v4;
      }
    }
  }
  __syncthreads();
  for (int g2=0; g2<2; ++g2){
    {
      short8 w[2][4];
#pragma unroll
      for (int ni=0;ni<2;++ni)
#pragma unroll
        for (int kk=0;kk<4;++kk)
          w[ni][kk] = *(const short8*)(V3 + ((size_t)((g2*8 + wid*2+ni)*4+kk)*64 + lane)*8);
      f32x4 b4[2];
      b4[0] = *(const f32x4*)(b3 + (g2*8 + wid*2+0)*16 + r0);
      b4[1] = *(const f32x4*)(b3 + (g2*8 + wid*2+1)*16 + r0);
      for (int mt=0; mt<10; ++mt){
        short8 bfr[4];
#pragma unroll
        for (int kk=0;kk<4;++kk) bfr[kk] = *(const short8*)(A + ((mt*4+kk)*64 + lane)*8);
#pragma unroll
        for (int ni=0;ni<2;++ni){
          int ntl = wid*2 + ni;
          f32x4 acc = {0.f,0.f,0.f,0.f};
#pragma unroll
          for (int kk=0;kk<4;++kk) acc = mfma16(w[ni][kk], bfr[kk], acc);
          short4v v4;
#pragma unroll
          for (int r=0;r<4;++r) v4[r] = (short)f2bf(fmaxf(acc[r] + b4[ni][r], 0.f));
          int kk2 = ntl >> 1, sub2 = (ntl & 1)*2 + (r0 >> 3);
          *(short4v*)(H1 + ((mt*4+kk2)*64 + sub2*16 + l15)*8 + (r0 & 4)) = v4;
        }
      }
    }
    __syncthreads();
    if (tid < 128){
      int p = tid >> 4, c8 = tid & 15;
      int kk = c8 >> 2, sub = c8 & 3;
      unsigned short mx[8];
#pragma unroll
      for (int e=0;e<8;++e) mx[e] = 0;
      for (int e=0;e<20;++e){
        int ee = e + p + c8; ee -= (ee >= 20) ? 20 : 0; ee -= (ee >= 20) ? 20 : 0;
        int row = p*20 + ee;
        short8 v = *(const short8*)(H1 + (((row>>4)*4 + kk)*64 + sub*16 + (row & 15))*8);
#pragma unroll
        for (int k2=0;k2<8;++k2){
          unsigned short u = (unsigned short)v[k2];
          mx[k2] = u > mx[k2] ? u : mx[k2];
        }
      }
      short8 o;
#pragma unroll
      for (int k2=0;k2<8;++k2) o[k2] = (short)mx[k2];
      *(short8*)(x2b + (size_t)(p0 + p)*256 + g2*128 + c8*8) = o;
    }
    __syncthreads();
  }
}

// ------------- lin0 (256->512) + relu + segment-max into pool -------------
__global__ __launch_bounds__(256) void lin0_k(const unsigned short* __restrict__ x2b, const unsigned short* __restrict__ W0s,
                                              const float* __restrict__ b0, unsigned* __restrict__ pool){
  __shared__ __align__(16) char smem[67584];
  unsigned short* A = (unsigned short*)(smem);        // [128][256] bf16 swizzled
  unsigned* ploc = (unsigned*)(smem + 65536);
  const int blk = blockIdx.x; const size_t row0 = (size_t)blk * 128; const int bb = blk >> 5;
  const int tid = threadIdx.x, lane = tid & 63, wid = tid >> 6;
  for (int it = tid; it < 4096; it += 256){
    int row = it >> 5, q = (it & 31) << 3;
    lds_put8(A, row, q, 256, 7, *(const short8*)(x2b + (row0 + row)*256 + q));
  }
  ploc[tid] = 0u; ploc[tid+256] = 0u;
  __syncthreads();
  const int l15 = lane & 15, kL = (lane >> 4) << 3;
  short8 af[2][8];
#pragma unroll
  for (int m=0;m<2;++m)
#pragma unroll
    for (int kk=0;kk<8;++kk)
      af[m][kk] = lds_frag(A, (wid*2+m)*16 + l15, kk*32 + kL, 256, 7);
  for (int nt=0; nt<32; ++nt){
    f32x4 a0 = {0.f,0.f,0.f,0.f}, a1 = {0.f,0.f,0.f,0.f};
#pragma unroll
    for (int kk=0;kk<8;++kk){
      short8 w = *(const short8*)(W0s + ((size_t)(nt*8+kk)*64 + lane)*8);
      a0 = mfma16(af[0][kk], w, a0);
      a1 = mfma16(af[1][kk], w, a1);
    }
    int col = nt*16 + l15;
    float m = fmaxf(fmaxf(fmaxf(a0[0],a0[1]),fmaxf(a0[2],a0[3])),
                    fmaxf(fmaxf(a1[0],a1[1]),fmaxf(a1[2],a1[3])));
    m = fmaxf(m + b0[col], 0.f);
    atomicMax(&ploc[col], __float_as_uint(m));
  }
  __syncthreads();
  atomicMax(&pool[(size_t)bb*512 + tid], ploc[tid]);
  atomicMax(&pool[(size_t)bb*512 + tid + 256], ploc[tid+256]);
}

// ------------- head: lin1+relu, lin2+relu, lin3, log_softmax -------------
__global__ __launch_bounds__(256) void head_k(const unsigned* __restrict__ pool,
    const float* __restrict__ w1, const float* __restrict__ bb1,
    const float* __restrict__ w2, const float* __restrict__ bb2,
    const float* __restrict__ w3, const float* __restrict__ bb3,
    float* __restrict__ out){
  __shared__ float pl[8*512];
  __shared__ float y1[8*256];
  __shared__ float y2[8*256];
  __shared__ float lg[8*40];
  const int tid = threadIdx.x;
  for (int it = tid; it < 4096; it += 256) pl[it] = __uint_as_float(pool[it]);
  __syncthreads();
  {
    float acc[8]; float bv = bb1[tid];
#pragma unroll
    for (int r=0;r<8;++r) acc[r] = bv;
    for (int k=0;k<512;++k){
      float w = w1[(size_t)k*256 + tid];
#pragma unroll
      for (int r=0;r<8;++r) acc[r] = fmaf(pl[r*512+k], w, acc[r]);
    }
#pragma unroll
    for (int r=0;r<8;++r) y1[r*256+tid] = fmaxf(acc[r], 0.f);
  }
  __syncthreads();
  {
    float acc[8]; float bv = bb2[tid];
#pragma unroll
    for (int r=0;r<8;++r) acc[r] = bv;
    for (int k=0;k<256;++k){
      float w = w2[(size_t)k*256 + tid];
#pragma unroll
      for (int r=0;r<8;++r) acc[r] = fmaf(y1[r*256+k], w, acc[r]);
    }
#pragma unroll
    for (int r=0;r<8;++r) y2[r*256+tid] = fmaxf(acc[r], 0.f);
  }
  __syncthreads();
  if (tid < 40){
    float acc[8]; float bv = bb3[tid];
#pragma unroll
    for (int r=0;r<8;++r) acc[r] = bv;
    for (int k=0;k<256;++k){
      float w = w3[(size_t)k*40 + tid];
#pragma unroll
      for (int r=0;r<8;++r) acc[r] = fmaf(y2[r*256+k], w, acc[r]);
    }
#pragma unroll
    for (int r=0;r<8;++r) lg[r*40+tid] = acc[r];
  }
  __syncthreads();
  if (tid < 8){
    float m = -__builtin_inff();
    for (int c2=0;c2<40;++c2) m = fmaxf(m, lg[tid*40+c2]);
    float s = 0.f;
    for (int c2=0;c2<40;++c2) s += expf(lg[tid*40+c2] - m);
    float L = logf(s);
    for (int c2=0;c2<40;++c2) out[tid*40+c2] = lg[tid*40+c2] - m - L;
  }
}

extern "C" void kernel_launch(void* const* d_in, const int* in_sizes, int n_in,
                              void* d_out, int out_size, void* d_ws, size_t ws_size,
                              hipStream_t stream){
  (void)in_sizes; (void)n_in; (void)out_size; (void)ws_size;
  const float* pos  = (const float*)d_in[0];
  const float* m1w1 = (const float*)d_in[2];  const float* m1b1 = (const float*)d_in[3];
  const float* m1w2 = (const float*)d_in[4];  const float* m1b2 = (const float*)d_in[5];
  const float* m1w3 = (const float*)d_in[6];  const float* m1b3 = (const float*)d_in[7];
  const float* m2w1 = (const float*)d_in[8];  const float* m2b1 = (const float*)d_in[9];
  const float* m2w2 = (const float*)d_in[10]; const float* m2b2 = (const float*)d_in[11];
  const float* m2w3 = (const float*)d_in[12]; const float* m2b3 = (const float*)d_in[13];
  const float* l0w  = (const float*)d_in[14]; const float* l0b  = (const float*)d_in[15];
  const float* l1w  = (const float*)d_in[16]; const float* l1b  = (const float*)d_in[17];
  const float* l2w  = (const float*)d_in[18]; const float* l2b  = (const float*)d_in[19];
  const float* l3w  = (const float*)d_in[20]; const float* l3b  = (const float*)d_in[21];

  char* ws = (char*)d_ws;
  size_t o = 0;
  auto alloc = [&](size_t bytes){ size_t r = o; o += (bytes + 255) & ~(size_t)255; return r; };
  size_t o_idx1 = alloc((size_t)NPTS*20*4);
  size_t o_idx2 = alloc((size_t)NPTS*20*4);
  size_t o_x1h  = alloc((size_t)NPTS*64*2);
  size_t o_x1l  = alloc((size_t)NPTS*64*2);
  size_t o_nrm  = alloc((size_t)NPTS*4);
  size_t o_x2b  = alloc((size_t)NPTS*256*2);
  size_t o_pool = alloc(8*512*4);
  size_t o_p3h  = alloc((size_t)NPTS*8*2);
  size_t o_p3l  = alloc((size_t)NPTS*8*2);
  size_t o_nrm3 = alloc((size_t)NPTS*4);
  size_t o_pk   = alloc((size_t)2*20*NPTS*4);
  size_t o_W1h = alloc(4*1*64*8*2),  o_W1l = alloc(4*1*64*8*2);
  size_t o_W2h = alloc(4*2*64*8*2),  o_W2l = alloc(4*2*64*8*2);
  size_t o_W3h = alloc(4*2*64*8*2),  o_W3l = alloc(4*2*64*8*2);
  size_t o_V1  = alloc(8*4*64*8*2);
  size_t o_V2  = alloc(8*4*64*8*2);
  size_t o_V3  = alloc(16*4*64*8*2);
  size_t o_W0  = alloc(32*8*64*8*2);

  hipMemsetAsync(ws + o_pool, 0, 8*512*4, stream);

  stage_w_k<<<1,256,0,stream>>>(m1w1, (unsigned short*)(ws+o_W1h), (unsigned short*)(ws+o_W1l), 6, 64, 1, 4);
  stage_w_k<<<2,256,0,stream>>>(m1w2, (unsigned short*)(ws+o_W2h), (unsigned short*)(ws+o_W2l), 64, 64, 2, 4);
  stage_w_k<<<2,256,0,stream>>>(m1w3, (unsigned short*)(ws+o_W3h), (unsigned short*)(ws+o_W3l), 64, 64, 2, 4);
  stage_w_k<<<8,256,0,stream>>>(m2w1, (unsigned short*)(ws+o_V1), nullptr, 128, 128, 4, 8);
  stage_w_k<<<8,256,0,stream>>>(m2w2, (unsigned short*)(ws+o_V2), nullptr, 128, 128, 4, 8);
  stage_w_k<<<16,256,0,stream>>>(m2w3, (unsigned short*)(ws+o_V3), nullptr, 128, 256, 4, 16);
  stage_w_k<<<64,256,0,stream>>>(l0w,  (unsigned short*)(ws+o_W0), nullptr, 256, 512, 8, 32);

  p3_k<<<128,256,0,stream>>>(pos, (unsigned short*)(ws+o_p3h), (unsigned short*)(ws+o_p3l), (float*)(ws+o_nrm3));

  knn_k<0><<<1024,256,0,stream>>>((const unsigned short*)(ws+o_p3h), (const unsigned short*)(ws+o_p3l),
                                  (const float*)(ws+o_nrm3), (unsigned*)(ws+o_pk));
  knn_merge_k<<<128,256,0,stream>>>((const unsigned*)(ws+o_pk), (int*)(ws+o_idx1));

  ec1_k<<<8192,256,0,stream>>>(pos, (const int*)(ws+o_idx1),
      (const unsigned short*)(ws+o_W1h), (const unsigned short*)(ws+o_W1l),
      (const unsigned short*)(ws+o_W2h), (const unsigned short*)(ws+o_W2l),
      (const unsigned short*)(ws+o_W3h), (const unsigned short*)(ws+o_W3l),
      m1b1, m1b2, m1b3,
      (unsigned short*)(ws+o_x1h), (unsigned short*)(ws+o_x1l), (float*)(ws+o_nrm));

  knn_k<1><<<1024,256,0,stream>>>((const unsigned short*)(ws+o_x1h), (const unsigned short*)(ws+o_x1l),
                                  (const float*)(ws+o_nrm), (unsigned*)(ws+o_pk));
  knn_merge_k<<<128,256,0,stream>>>((const unsigned*)(ws+o_pk), (int*)(ws+o_idx2));

  ec2_k<<<4096,256,0,stream>>>((const unsigned short*)(ws+o_x1h), (const int*)(ws+o_idx2),
      (const unsigned short*)(ws+o_V1), (const unsigned short*)(ws+o_V2), (const unsigned short*)(ws+o_V3),
      m2b1, m2b2, m2b3, (unsigned short*)(ws+o_x2b));

  lin0_k<<<256,256,0,stream>>>((const unsigned short*)(ws+o_x2b), (const unsigned short*)(ws+o_W0),
                               l0b, (unsigned*)(ws+o_pool));

  head_k<<<1,256,0,stream>>>((const unsigned*)(ws+o_pool), l1w, l1b, l2w, l2b, l3w, l3b, (float*)d_out);
}